// Round 1
// baseline (3498.788 us; speedup 1.0000x reference)
//
#include <hip/hip_runtime.h>
#include <hip/hip_bf16.h>
#include <cstdint>
#include <cstddef>

// Problem constants (VulnDetector): B=64, N=50000, E=300000, NF=128, G=256, H=512, R=3, L=2
constexpr int GDIM = 256;   // graph hidden
constexpr int HDIM = 512;   // fusion hidden
constexpr int NF   = 128;   // node features

// ---------------- tiled fp32 GEMM ----------------
// C[M, 256] = op(A)[M,K] @ B[K,256] (+bias); op = optional relu on A-read.
// Grid: (ceil(M/128), 4). C written with row stride ldc at column blockIdx.y*64
// (C pointer may be pre-offset for relation slots in the y buffer).
#define BM 128
#define BN 64
#define BK 16
#define AS_STRIDE 132   // pad: bank = (4k + m) % 32 -> 2-way max (free), 16B-aligned rows

__global__ __launch_bounds__(256) void gemm_f32(
    const float* __restrict__ A, const float* __restrict__ B,
    const float* __restrict__ bias, float* __restrict__ C,
    int M, int K, int ldb, int ldc, int relu_a)
{
  __shared__ float As[BK * AS_STRIDE];  // transposed: As[k][m]
  __shared__ float Bs[BK * BN];         // Bs[k][n]
  const int t    = threadIdx.x;
  const int row0 = blockIdx.x * BM;
  const int col0 = blockIdx.y * BN;
  const int tx   = t & 15;   // -> 4 output cols
  const int ty   = t >> 4;   // -> 8 output rows

  float acc[8][4];
#pragma unroll
  for (int i = 0; i < 8; ++i)
#pragma unroll
    for (int j = 0; j < 4; ++j) acc[i][j] = 0.f;

  for (int k0 = 0; k0 < K; k0 += BK) {
    __syncthreads();  // previous compute done before overwriting LDS
    // stage A: 128x16, two float4 per thread, stored transposed
#pragma unroll
    for (int p = 0; p < 2; ++p) {
      int q   = p * 256 + t;
      int row = q >> 2;
      int kq  = (q & 3) * 4;
      float4 v = make_float4(0.f, 0.f, 0.f, 0.f);
      if (row0 + row < M)
        v = *reinterpret_cast<const float4*>(A + (size_t)(row0 + row) * K + k0 + kq);
      if (relu_a) {
        v.x = fmaxf(v.x, 0.f); v.y = fmaxf(v.y, 0.f);
        v.z = fmaxf(v.z, 0.f); v.w = fmaxf(v.w, 0.f);
      }
      As[(kq + 0) * AS_STRIDE + row] = v.x;
      As[(kq + 1) * AS_STRIDE + row] = v.y;
      As[(kq + 2) * AS_STRIDE + row] = v.z;
      As[(kq + 3) * AS_STRIDE + row] = v.w;
    }
    // stage B: 16x64, one float4 per thread
    {
      int k = t >> 4, n4 = (t & 15) * 4;
      float4 v = *reinterpret_cast<const float4*>(B + (size_t)(k0 + k) * ldb + col0 + n4);
      *reinterpret_cast<float4*>(&Bs[k * BN + n4]) = v;
    }
    __syncthreads();
#pragma unroll
    for (int kk = 0; kk < BK; ++kk) {
      float4 a0 = *reinterpret_cast<const float4*>(&As[kk * AS_STRIDE + ty * 8]);
      float4 a1 = *reinterpret_cast<const float4*>(&As[kk * AS_STRIDE + ty * 8 + 4]);
      float4 b0 = *reinterpret_cast<const float4*>(&Bs[kk * BN + tx * 4]);
      const float av[8] = {a0.x, a0.y, a0.z, a0.w, a1.x, a1.y, a1.z, a1.w};
      const float bw[4] = {b0.x, b0.y, b0.z, b0.w};
#pragma unroll
      for (int i = 0; i < 8; ++i)
#pragma unroll
        for (int j = 0; j < 4; ++j)
          acc[i][j] = fmaf(av[i], bw[j], acc[i][j]);
    }
  }

#pragma unroll
  for (int i = 0; i < 8; ++i) {
    int row = row0 + ty * 8 + i;
    if (row < M) {
      float4 o = make_float4(acc[i][0], acc[i][1], acc[i][2], acc[i][3]);
      if (bias) {
        o.x += bias[col0 + tx * 4 + 0]; o.y += bias[col0 + tx * 4 + 1];
        o.z += bias[col0 + tx * 4 + 2]; o.w += bias[col0 + tx * 4 + 3];
      }
      *reinterpret_cast<float4*>(C + (size_t)row * ldc + col0 + tx * 4) = o;
    }
  }
}

// ---------------- edge scatter: out[dst] += y[src, et, :] ----------------
// 1 edge per 64-lane wave, 4 edges per block. y layout: [N][3][256].
__global__ __launch_bounds__(256) void scatter_kernel(
    const int* __restrict__ src, const int* __restrict__ dst,
    const int* __restrict__ et, const float* __restrict__ y,
    float* __restrict__ out, int E)
{
  int e = blockIdx.x * 4 + (threadIdx.x >> 6);
  if (e >= E) return;
  int lane = threadIdx.x & 63;
  int s = src[e], d = dst[e], r = et[e];
  float4 v = *reinterpret_cast<const float4*>(y + (size_t)s * (3 * GDIM) + r * GDIM + lane * 4);
  float* o = out + (size_t)d * GDIM + lane * 4;
  atomicAdd(o + 0, v.x);
  atomicAdd(o + 1, v.y);
  atomicAdd(o + 2, v.z);
  atomicAdd(o + 3, v.w);
}

// ---------------- mean-pool (with relu on read): hg[b] += relu(x[n]), cnt[b] += 1 ----------------
// Block handles 128 consecutive nodes; bv is sorted so runs are long -> few atomics.
__global__ __launch_bounds__(256) void pool_kernel(
    const float* __restrict__ x, const int* __restrict__ bv,
    float* __restrict__ hg, float* __restrict__ cnt, int N)
{
  __shared__ int sbv[128];
  int n0 = blockIdx.x * 128;
  int t = threadIdx.x;
  int nmax = min(128, N - n0);
  if (t < nmax) sbv[t] = bv[n0 + t];
  __syncthreads();
  // thread t owns column t
  float run = 0.f;
  int cur = sbv[0];
  for (int i = 0; i < nmax; ++i) {
    int b = sbv[i];                        // uniform across threads
    if (b != cur) { atomicAdd(&hg[cur * GDIM + t], run); run = 0.f; cur = b; }
    run += fmaxf(x[(size_t)(n0 + i) * GDIM + t], 0.f);
  }
  atomicAdd(&hg[cur * GDIM + t], run);
  if (t == 0) {
    float c = 0.f; int cb = sbv[0];
    for (int i = 0; i < nmax; ++i) {
      int b = sbv[i];
      if (b != cb) { atomicAdd(&cnt[cb], c); c = 0.f; cb = b; }
      c += 1.f;
    }
    atomicAdd(&cnt[cb], c);
  }
}

// ---------------- small dense layers ----------------
// Y[b, j] = relu?(X[b,:] @ W[:, j] + bias[j]); W row-major [K, Ncols]
__global__ __launch_bounds__(256) void dense_rowmajor(
    const float* __restrict__ X, const float* __restrict__ W,
    const float* __restrict__ bias, float* __restrict__ Y,
    int K, int Ncols, int relu_out)
{
  int b = blockIdx.x;
  int j = blockIdx.y * 256 + threadIdx.x;
  if (j >= Ncols) return;
  const float* xr = X + (size_t)b * K;
  float s = bias ? bias[j] : 0.f;
  for (int k = 0; k < K; ++k) s = fmaf(xr[k], W[(size_t)k * Ncols + j], s);
  if (relu_out) s = fmaxf(s, 0.f);
  Y[(size_t)b * Ncols + j] = s;
}

// hgp[b, j] = (hg[b,:]/max(cnt,1)) @ graph_w[:, j] + graph_b[j]
__global__ __launch_bounds__(256) void graph_proj_kernel(
    const float* __restrict__ hg, const float* __restrict__ cnt,
    const float* __restrict__ W, const float* __restrict__ bias,
    float* __restrict__ Y)
{
  int b = blockIdx.x;
  int j = blockIdx.y * 256 + threadIdx.x;  // < 512
  float inv = 1.f / fmaxf(cnt[b], 1.f);
  const float* hr = hg + (size_t)b * GDIM;
  float s = 0.f;
  for (int k = 0; k < GDIM; ++k) s = fmaf(hr[k], W[(size_t)k * HDIM + j], s);
  Y[(size_t)b * HDIM + j] = s * inv + bias[j];
}

// g = sigmoid([h, hgp] @ gate_w + gate_b); f = g*h + (1-g)*hgp
__global__ __launch_bounds__(256) void gate_fuse_kernel(
    const float* __restrict__ h, const float* __restrict__ hgp,
    const float* __restrict__ gw, const float* __restrict__ gb,
    float* __restrict__ f)
{
  int b = blockIdx.x;
  int j = blockIdx.y * 256 + threadIdx.x;  // < 512
  const float* hr = h + (size_t)b * HDIM;
  const float* gr = hgp + (size_t)b * HDIM;
  float s = gb[j];
  for (int k = 0; k < HDIM; ++k) s = fmaf(hr[k], gw[(size_t)k * HDIM + j], s);
  for (int k = 0; k < HDIM; ++k) s = fmaf(gr[k], gw[(size_t)(HDIM + k) * HDIM + j], s);
  float g = 1.f / (1.f + expf(-s));
  f[(size_t)b * HDIM + j] = g * hr[j] + (1.f - g) * gr[j];
}

extern "C" void kernel_launch(void* const* d_in, const int* in_sizes, int n_in,
                              void* d_out, int out_size, void* d_ws, size_t ws_size,
                              hipStream_t stream)
{
  const float* cls     = (const float*)d_in[0];
  const float* nf      = (const float*)d_in[1];
  const int*   ei      = (const int*)d_in[2];
  const int*   et      = (const int*)d_in[3];
  const int*   bv      = (const int*)d_in[4];
  const float* node_w  = (const float*)d_in[5];
  const float* node_b  = (const float*)d_in[6];
  const float* rel_w   = (const float*)d_in[7];
  const float* self_w  = (const float*)d_in[8];
  const float* self_b  = (const float*)d_in[9];
  const float* text_w  = (const float*)d_in[10];
  const float* text_b  = (const float*)d_in[11];
  const float* graph_w = (const float*)d_in[12];
  const float* graph_b = (const float*)d_in[13];
  const float* gate_w  = (const float*)d_in[14];
  const float* gate_b  = (const float*)d_in[15];
  const float* c1_w    = (const float*)d_in[16];
  const float* c1_b    = (const float*)d_in[17];
  const float* c2_w    = (const float*)d_in[18];
  const float* c2_b    = (const float*)d_in[19];

  const int Bsz = in_sizes[0] / 768;   // 64
  const int Nn  = in_sizes[1] / NF;    // 50000
  const int E   = in_sizes[3];         // 300000

  const int* src = ei;
  const int* dst = ei + E;

  // workspace layout (floats); total ~64.2M floats (~257 MB)
  float* ws = (float*)d_ws;
  size_t off = 0;
  float* x0  = ws + off; off += (size_t)Nn * GDIM;       // node states (ping)
  float* x1  = ws + off; off += (size_t)Nn * GDIM;       // node states (pong)
  float* y   = ws + off; off += (size_t)Nn * 3 * GDIM;   // per-relation transforms [N][3][256]
  float* h   = ws + off; off += (size_t)Bsz * HDIM;      // text embedding
  float* hg  = ws + off; off += (size_t)Bsz * GDIM;      // pooled graph sum
  float* cnt = ws + off; off += (size_t)Bsz;             // node counts
  float* hgp = ws + off; off += (size_t)Bsz * HDIM;      // graph embedding
  float* f   = ws + off; off += (size_t)Bsz * HDIM;      // fused
  float* z   = ws + off; off += (size_t)Bsz * (HDIM/2);  // classifier hidden

  dim3 blk(256);

  // zero pooled accumulators (hg, cnt contiguous)
  hipMemsetAsync(hg, 0, (size_t)(Bsz * GDIM + Bsz) * sizeof(float), stream);

  // text projection: h = cls @ text_w + text_b
  dense_rowmajor<<<dim3(Bsz, 2), blk, 0, stream>>>(cls, text_w, text_b, h, 768, HDIM, 0);

  // node projection: x0 = nf @ node_w + node_b
  dim3 ggrid((Nn + BM - 1) / BM, 4);
  gemm_f32<<<ggrid, blk, 0, stream>>>(nf, node_w, node_b, x0, Nn, NF, GDIM, GDIM, 0);

  // RGCN layers
  for (int l = 0; l < 2; ++l) {
    const float* A = l ? x1 : x0;
    float* outb    = l ? x0 : x1;
    int relu_a     = l ? 1 : 0;  // layer inputs are relu(prev out) except layer 0
    // self-loop: out = relu?(A) @ self_w[l] + self_b[l]
    gemm_f32<<<ggrid, blk, 0, stream>>>(A, self_w + (size_t)l * GDIM * GDIM,
                                        self_b + (size_t)l * GDIM, outb,
                                        Nn, GDIM, GDIM, GDIM, relu_a);
    // relation transforms: y[:, r, :] = relu?(A) @ rel_w[l, r]
    for (int r = 0; r < 3; ++r)
      gemm_f32<<<ggrid, blk, 0, stream>>>(A, rel_w + ((size_t)l * 3 + r) * GDIM * GDIM,
                                          nullptr, y + (size_t)r * GDIM,
                                          Nn, GDIM, GDIM, 3 * GDIM, relu_a);
    // message passing: out[dst] += y[src, et, :]
    scatter_kernel<<<dim3((E + 3) / 4), blk, 0, stream>>>(src, dst, et, y, outb, E);
  }

  // mean pool (applies final relu on read): hg, cnt
  pool_kernel<<<dim3((Nn + 127) / 128), blk, 0, stream>>>(x0, bv, hg, cnt, Nn);

  // graph projection
  graph_proj_kernel<<<dim3(Bsz, 2), blk, 0, stream>>>(hg, cnt, graph_w, graph_b, hgp);

  // gated fusion
  gate_fuse_kernel<<<dim3(Bsz, 2), blk, 0, stream>>>(h, hgp, gate_w, gate_b, f);

  // classifier
  dense_rowmajor<<<dim3(Bsz, 1), blk, 0, stream>>>(f, c1_w, c1_b, z, HDIM, HDIM / 2, 1);
  dense_rowmajor<<<dim3(Bsz, 1), blk, 0, stream>>>(z, c2_w, c2_b, (float*)d_out, HDIM / 2, 2, 0);
}

// Round 2
// 1660.051 us; speedup vs baseline: 2.1076x; 2.1076x over previous
//
#include <hip/hip_runtime.h>
#include <hip/hip_bf16.h>
#include <cstdint>
#include <cstddef>

// Problem constants (VulnDetector): B=64, N=50000, E=300000, NF=128, G=256, H=512, R=3, L=2
constexpr int GDIM = 256;   // graph hidden
constexpr int HDIM = 512;   // fusion hidden
constexpr int NF   = 128;   // node features

// ---------------- tiled fp32 GEMM ----------------
// C[M, 256] = op(A)[M,K] @ B[K,256] (+bias); op = optional relu on A-read.
// Grid: (ceil(M/128), 4). C written with row stride ldc at column blockIdx.y*64.
#define BM 128
#define BN 64
#define BK 16
#define AS_STRIDE 132   // pad: bank = (4k + m) % 32 -> 2-way max (free), 16B-aligned rows

__global__ __launch_bounds__(256) void gemm_f32(
    const float* __restrict__ A, const float* __restrict__ B,
    const float* __restrict__ bias, float* __restrict__ C,
    int M, int K, int ldb, int ldc, int relu_a)
{
  __shared__ float As[BK * AS_STRIDE];  // transposed: As[k][m]
  __shared__ float Bs[BK * BN];         // Bs[k][n]
  const int t    = threadIdx.x;
  const int row0 = blockIdx.x * BM;
  const int col0 = blockIdx.y * BN;
  const int tx   = t & 15;   // -> 4 output cols
  const int ty   = t >> 4;   // -> 8 output rows

  float acc[8][4];
#pragma unroll
  for (int i = 0; i < 8; ++i)
#pragma unroll
    for (int j = 0; j < 4; ++j) acc[i][j] = 0.f;

  for (int k0 = 0; k0 < K; k0 += BK) {
    __syncthreads();  // previous compute done before overwriting LDS
    // stage A: 128x16, two float4 per thread, stored transposed
#pragma unroll
    for (int p = 0; p < 2; ++p) {
      int q   = p * 256 + t;
      int row = q >> 2;
      int kq  = (q & 3) * 4;
      float4 v = make_float4(0.f, 0.f, 0.f, 0.f);
      if (row0 + row < M)
        v = *reinterpret_cast<const float4*>(A + (size_t)(row0 + row) * K + k0 + kq);
      if (relu_a) {
        v.x = fmaxf(v.x, 0.f); v.y = fmaxf(v.y, 0.f);
        v.z = fmaxf(v.z, 0.f); v.w = fmaxf(v.w, 0.f);
      }
      As[(kq + 0) * AS_STRIDE + row] = v.x;
      As[(kq + 1) * AS_STRIDE + row] = v.y;
      As[(kq + 2) * AS_STRIDE + row] = v.z;
      As[(kq + 3) * AS_STRIDE + row] = v.w;
    }
    // stage B: 16x64, one float4 per thread
    {
      int k = t >> 4, n4 = (t & 15) * 4;
      float4 v = *reinterpret_cast<const float4*>(B + (size_t)(k0 + k) * ldb + col0 + n4);
      *reinterpret_cast<float4*>(&Bs[k * BN + n4]) = v;
    }
    __syncthreads();
#pragma unroll
    for (int kk = 0; kk < BK; ++kk) {
      float4 a0 = *reinterpret_cast<const float4*>(&As[kk * AS_STRIDE + ty * 8]);
      float4 a1 = *reinterpret_cast<const float4*>(&As[kk * AS_STRIDE + ty * 8 + 4]);
      float4 b0 = *reinterpret_cast<const float4*>(&Bs[kk * BN + tx * 4]);
      const float av[8] = {a0.x, a0.y, a0.z, a0.w, a1.x, a1.y, a1.z, a1.w};
      const float bw[4] = {b0.x, b0.y, b0.z, b0.w};
#pragma unroll
      for (int i = 0; i < 8; ++i)
#pragma unroll
        for (int j = 0; j < 4; ++j)
          acc[i][j] = fmaf(av[i], bw[j], acc[i][j]);
    }
  }

#pragma unroll
  for (int i = 0; i < 8; ++i) {
    int row = row0 + ty * 8 + i;
    if (row < M) {
      float4 o = make_float4(acc[i][0], acc[i][1], acc[i][2], acc[i][3]);
      if (bias) {
        o.x += bias[col0 + tx * 4 + 0]; o.y += bias[col0 + tx * 4 + 1];
        o.z += bias[col0 + tx * 4 + 2]; o.w += bias[col0 + tx * 4 + 3];
      }
      *reinterpret_cast<float4*>(C + (size_t)row * ldc + col0 + tx * 4) = o;
    }
  }
}

// ---------------- CSR build (by dst) ----------------
__global__ __launch_bounds__(256) void histo_kernel(
    const int* __restrict__ dst, int* __restrict__ deg, int E)
{
  int e = blockIdx.x * 256 + threadIdx.x;
  if (e < E) atomicAdd(&deg[dst[e]], 1);
}

// inclusive scan per 256-block + block sums
__global__ __launch_bounds__(256) void scan_partial(
    const int* __restrict__ deg, int* __restrict__ incl, int* __restrict__ bsum, int N)
{
  __shared__ int s[256];
  int t = threadIdx.x;
  int n = blockIdx.x * 256 + t;
  int v = (n < N) ? deg[n] : 0;
  s[t] = v;
  __syncthreads();
#pragma unroll
  for (int o = 1; o < 256; o <<= 1) {
    int u = (t >= o) ? s[t - o] : 0;
    __syncthreads();
    s[t] += u;
    __syncthreads();
  }
  if (n < N) incl[n] = s[t];
  if (t == 255) bsum[blockIdx.x] = s[255];
}

// exclusive scan of block sums (nb <= 256), in place
__global__ __launch_bounds__(256) void scan_sums(int* __restrict__ bsum, int nb)
{
  __shared__ int s[256];
  int t = threadIdx.x;
  int v = (t < nb) ? bsum[t] : 0;
  s[t] = v;
  __syncthreads();
#pragma unroll
  for (int o = 1; o < 256; o <<= 1) {
    int u = (t >= o) ? s[t - o] : 0;
    __syncthreads();
    s[t] += u;
    __syncthreads();
  }
  if (t < nb) bsum[t] = s[t] - v;  // exclusive
}

// off[n] = exclusive prefix; off[N] = E
__global__ __launch_bounds__(256) void scan_add(
    const int* __restrict__ incl, const int* __restrict__ deg,
    const int* __restrict__ bsum, int* __restrict__ off, int N, int E)
{
  int n = blockIdx.x * 256 + threadIdx.x;
  if (n < N) off[n] = incl[n] - deg[n] + bsum[n >> 8];
  if (n == 0) off[N] = E;
}

// place each edge's (src, rel) at its slot in the dst-sorted order
__global__ __launch_bounds__(256) void fill_kernel(
    const int* __restrict__ src, const int* __restrict__ dst,
    const int* __restrict__ et, const int* __restrict__ off,
    int* __restrict__ cursor, int* __restrict__ psrc, int* __restrict__ prel, int E)
{
  int e = blockIdx.x * 256 + threadIdx.x;
  if (e >= E) return;
  int d = dst[e];
  int pos = atomicAdd(&cursor[d], 1);
  int idx = off[d] + pos;
  psrc[idx] = src[e];
  prel[idx] = et[e];
}

// ---------------- aggregation: out[n] += sum over incoming edges of y[src, rel, :] ----------------
// One 64-lane wave per node; no atomics (wave owns the output row).
__global__ __launch_bounds__(256) void aggregate_kernel(
    const int* __restrict__ off, const int* __restrict__ psrc,
    const int* __restrict__ prel, const float* __restrict__ y,
    float* __restrict__ out, int N)
{
  int n = blockIdx.x * 4 + (threadIdx.x >> 6);
  if (n >= N) return;
  int lane = threadIdx.x & 63;
  int i0 = off[n], i1 = off[n + 1];
  float* o = out + (size_t)n * GDIM + lane * 4;
  float4 acc = *reinterpret_cast<const float4*>(o);  // self-loop result already there
  for (int i = i0; i < i1; ++i) {
    int s = psrc[i], r = prel[i];
    float4 v = *reinterpret_cast<const float4*>(y + (size_t)s * (3 * GDIM) + r * GDIM + lane * 4);
    acc.x += v.x; acc.y += v.y; acc.z += v.z; acc.w += v.w;
  }
  *reinterpret_cast<float4*>(o) = acc;
}

// ---------------- mean-pool (with relu on read) ----------------
__global__ __launch_bounds__(256) void pool_kernel(
    const float* __restrict__ x, const int* __restrict__ bv,
    float* __restrict__ hg, float* __restrict__ cnt, int N)
{
  __shared__ int sbv[128];
  int n0 = blockIdx.x * 128;
  int t = threadIdx.x;
  int nmax = min(128, N - n0);
  if (t < nmax) sbv[t] = bv[n0 + t];
  __syncthreads();
  float run = 0.f;
  int cur = sbv[0];
  for (int i = 0; i < nmax; ++i) {
    int b = sbv[i];
    if (b != cur) { atomicAdd(&hg[cur * GDIM + t], run); run = 0.f; cur = b; }
    run += fmaxf(x[(size_t)(n0 + i) * GDIM + t], 0.f);
  }
  atomicAdd(&hg[cur * GDIM + t], run);
  if (t == 0) {
    float c = 0.f; int cb = sbv[0];
    for (int i = 0; i < nmax; ++i) {
      int b = sbv[i];
      if (b != cb) { atomicAdd(&cnt[cb], c); c = 0.f; cb = b; }
      c += 1.f;
    }
    atomicAdd(&cnt[cb], c);
  }
}

// ---------------- small dense layers ----------------
__global__ __launch_bounds__(256) void dense_rowmajor(
    const float* __restrict__ X, const float* __restrict__ W,
    const float* __restrict__ bias, float* __restrict__ Y,
    int K, int Ncols, int relu_out)
{
  int b = blockIdx.x;
  int j = blockIdx.y * 256 + threadIdx.x;
  if (j >= Ncols) return;
  const float* xr = X + (size_t)b * K;
  float s = bias ? bias[j] : 0.f;
  for (int k = 0; k < K; ++k) s = fmaf(xr[k], W[(size_t)k * Ncols + j], s);
  if (relu_out) s = fmaxf(s, 0.f);
  Y[(size_t)b * Ncols + j] = s;
}

__global__ __launch_bounds__(256) void graph_proj_kernel(
    const float* __restrict__ hg, const float* __restrict__ cnt,
    const float* __restrict__ W, const float* __restrict__ bias,
    float* __restrict__ Y)
{
  int b = blockIdx.x;
  int j = blockIdx.y * 256 + threadIdx.x;  // < 512
  float inv = 1.f / fmaxf(cnt[b], 1.f);
  const float* hr = hg + (size_t)b * GDIM;
  float s = 0.f;
  for (int k = 0; k < GDIM; ++k) s = fmaf(hr[k], W[(size_t)k * HDIM + j], s);
  Y[(size_t)b * HDIM + j] = s * inv + bias[j];
}

__global__ __launch_bounds__(256) void gate_fuse_kernel(
    const float* __restrict__ h, const float* __restrict__ hgp,
    const float* __restrict__ gw, const float* __restrict__ gb,
    float* __restrict__ f)
{
  int b = blockIdx.x;
  int j = blockIdx.y * 256 + threadIdx.x;  // < 512
  const float* hr = h + (size_t)b * HDIM;
  const float* gr = hgp + (size_t)b * HDIM;
  float s = gb[j];
  for (int k = 0; k < HDIM; ++k) s = fmaf(hr[k], gw[(size_t)k * HDIM + j], s);
  for (int k = 0; k < HDIM; ++k) s = fmaf(gr[k], gw[(size_t)(HDIM + k) * HDIM + j], s);
  float g = 1.f / (1.f + expf(-s));
  f[(size_t)b * HDIM + j] = g * hr[j] + (1.f - g) * gr[j];
}

extern "C" void kernel_launch(void* const* d_in, const int* in_sizes, int n_in,
                              void* d_out, int out_size, void* d_ws, size_t ws_size,
                              hipStream_t stream)
{
  const float* cls     = (const float*)d_in[0];
  const float* nf      = (const float*)d_in[1];
  const int*   ei      = (const int*)d_in[2];
  const int*   et      = (const int*)d_in[3];
  const int*   bv      = (const int*)d_in[4];
  const float* node_w  = (const float*)d_in[5];
  const float* node_b  = (const float*)d_in[6];
  const float* rel_w   = (const float*)d_in[7];
  const float* self_w  = (const float*)d_in[8];
  const float* self_b  = (const float*)d_in[9];
  const float* text_w  = (const float*)d_in[10];
  const float* text_b  = (const float*)d_in[11];
  const float* graph_w = (const float*)d_in[12];
  const float* graph_b = (const float*)d_in[13];
  const float* gate_w  = (const float*)d_in[14];
  const float* gate_b  = (const float*)d_in[15];
  const float* c1_w    = (const float*)d_in[16];
  const float* c1_b    = (const float*)d_in[17];
  const float* c2_w    = (const float*)d_in[18];
  const float* c2_b    = (const float*)d_in[19];

  const int Bsz = in_sizes[0] / 768;   // 64
  const int Nn  = in_sizes[1] / NF;    // 50000
  const int E   = in_sizes[3];         // 300000

  const int* src = ei;
  const int* dst = ei + E;

  // ---------------- workspace layout ----------------
  float* ws = (float*)d_ws;
  size_t off_f = 0;
  float* x0  = ws + off_f; off_f += (size_t)Nn * GDIM;       // node states (ping)
  float* x1  = ws + off_f; off_f += (size_t)Nn * GDIM;       // node states (pong)
  float* y   = ws + off_f; off_f += (size_t)Nn * 3 * GDIM;   // per-relation transforms [N][3][256]
  float* h   = ws + off_f; off_f += (size_t)Bsz * HDIM;
  float* hg  = ws + off_f; off_f += (size_t)Bsz * GDIM;
  float* cnt = ws + off_f; off_f += (size_t)Bsz;
  float* hgp = ws + off_f; off_f += (size_t)Bsz * HDIM;
  float* f   = ws + off_f; off_f += (size_t)Bsz * HDIM;
  float* z   = ws + off_f; off_f += (size_t)Bsz * (HDIM/2);
  // persistent CSR (lives across both layers)
  int* csr_off = (int*)(ws + off_f);          // N+1
  int* psrc    = csr_off + (Nn + 1);          // E
  int* prel    = psrc + E;                    // E
  // transient CSR-build scratch overlaid on x1 (x1 first written AFTER build)
  int* deg    = (int*)x1;       // N
  int* incl   = deg + Nn;       // N
  int* cursor = incl + Nn;      // N
  int* bsum   = cursor + Nn;    // 256

  dim3 blk(256);
  const int nbN = (Nn + 255) / 256;   // 196
  const int nbE = (E + 255) / 256;

  // ---------------- CSR build (once; reused by both layers) ----------------
  hipMemsetAsync(deg, 0, (size_t)(3 * Nn + 256) * sizeof(int), stream);  // deg+incl+cursor+bsum
  histo_kernel<<<nbE, blk, 0, stream>>>(dst, deg, E);
  scan_partial<<<nbN, blk, 0, stream>>>(deg, incl, bsum, Nn);
  scan_sums<<<1, blk, 0, stream>>>(bsum, nbN);
  scan_add<<<nbN, blk, 0, stream>>>(incl, deg, bsum, csr_off, Nn, E);
  fill_kernel<<<nbE, blk, 0, stream>>>(src, dst, et, csr_off, cursor, psrc, prel, E);

  // zero pooled accumulators (hg, cnt contiguous)
  hipMemsetAsync(hg, 0, (size_t)(Bsz * GDIM + Bsz) * sizeof(float), stream);

  // text projection: h = cls @ text_w + text_b
  dense_rowmajor<<<dim3(Bsz, 2), blk, 0, stream>>>(cls, text_w, text_b, h, 768, HDIM, 0);

  // node projection: x0 = nf @ node_w + node_b
  dim3 ggrid((Nn + BM - 1) / BM, 4);
  gemm_f32<<<ggrid, blk, 0, stream>>>(nf, node_w, node_b, x0, Nn, NF, GDIM, GDIM, 0);

  // RGCN layers
  for (int l = 0; l < 2; ++l) {
    const float* A = l ? x1 : x0;
    float* outb    = l ? x0 : x1;
    int relu_a     = l ? 1 : 0;
    // self-loop: out = relu?(A) @ self_w[l] + self_b[l]
    gemm_f32<<<ggrid, blk, 0, stream>>>(A, self_w + (size_t)l * GDIM * GDIM,
                                        self_b + (size_t)l * GDIM, outb,
                                        Nn, GDIM, GDIM, GDIM, relu_a);
    // relation transforms: y[:, r, :] = relu?(A) @ rel_w[l, r]
    for (int r = 0; r < 3; ++r)
      gemm_f32<<<ggrid, blk, 0, stream>>>(A, rel_w + ((size_t)l * 3 + r) * GDIM * GDIM,
                                          nullptr, y + (size_t)r * GDIM,
                                          Nn, GDIM, GDIM, 3 * GDIM, relu_a);
    // message passing via CSR gather (no atomics)
    aggregate_kernel<<<dim3((Nn + 3) / 4), blk, 0, stream>>>(csr_off, psrc, prel, y, outb, Nn);
  }

  // mean pool (applies final relu on read)
  pool_kernel<<<dim3((Nn + 127) / 128), blk, 0, stream>>>(x0, bv, hg, cnt, Nn);

  // graph projection
  graph_proj_kernel<<<dim3(Bsz, 2), blk, 0, stream>>>(hg, cnt, graph_w, graph_b, hgp);

  // gated fusion
  gate_fuse_kernel<<<dim3(Bsz, 2), blk, 0, stream>>>(h, hgp, gate_w, gate_b, f);

  // classifier
  dense_rowmajor<<<dim3(Bsz, 1), blk, 0, stream>>>(f, c1_w, c1_b, z, HDIM, HDIM / 2, 1);
  dense_rowmajor<<<dim3(Bsz, 1), blk, 0, stream>>>(z, c2_w, c2_b, (float*)d_out, HDIM / 2, 2, 0);
}

// Round 3
// 1194.804 us; speedup vs baseline: 2.9283x; 1.3894x over previous
//
#include <hip/hip_runtime.h>
#include <hip/hip_bf16.h>
#include <cstdint>
#include <cstddef>

// Problem constants (VulnDetector): B=64, N=50000, E=300000, NF=128, G=256, H=512, R=3, L=2
constexpr int GDIM = 256;   // graph hidden
constexpr int HDIM = 512;   // fusion hidden
constexpr int NF   = 128;   // node features

// ---------------- tiled fp32 GEMM ----------------
// C[M, 256] = op(A)[M,K] @ B[K,256] (+bias); op = optional relu on A-read.
// Grid: (ceil(M/128), 4). C written with row stride ldc at column blockIdx.y*64.
#define BM 128
#define BN 64
#define BK 16
#define AS_STRIDE 132   // pad: bank = (4k + m) % 32 -> 2-way max (free), 16B-aligned rows

__global__ __launch_bounds__(256) void gemm_f32(
    const float* __restrict__ A, const float* __restrict__ B,
    const float* __restrict__ bias, float* __restrict__ C,
    int M, int K, int ldb, int ldc, int relu_a)
{
  __shared__ float As[BK * AS_STRIDE];  // transposed: As[k][m]
  __shared__ float Bs[BK * BN];         // Bs[k][n]
  const int t    = threadIdx.x;
  const int row0 = blockIdx.x * BM;
  const int col0 = blockIdx.y * BN;
  const int tx   = t & 15;   // -> 4 output cols
  const int ty   = t >> 4;   // -> 8 output rows

  float acc[8][4];
#pragma unroll
  for (int i = 0; i < 8; ++i)
#pragma unroll
    for (int j = 0; j < 4; ++j) acc[i][j] = 0.f;

  for (int k0 = 0; k0 < K; k0 += BK) {
    __syncthreads();  // previous compute done before overwriting LDS
    // stage A: 128x16, two float4 per thread, stored transposed
#pragma unroll
    for (int p = 0; p < 2; ++p) {
      int q   = p * 256 + t;
      int row = q >> 2;
      int kq  = (q & 3) * 4;
      float4 v = make_float4(0.f, 0.f, 0.f, 0.f);
      if (row0 + row < M)
        v = *reinterpret_cast<const float4*>(A + (size_t)(row0 + row) * K + k0 + kq);
      if (relu_a) {
        v.x = fmaxf(v.x, 0.f); v.y = fmaxf(v.y, 0.f);
        v.z = fmaxf(v.z, 0.f); v.w = fmaxf(v.w, 0.f);
      }
      As[(kq + 0) * AS_STRIDE + row] = v.x;
      As[(kq + 1) * AS_STRIDE + row] = v.y;
      As[(kq + 2) * AS_STRIDE + row] = v.z;
      As[(kq + 3) * AS_STRIDE + row] = v.w;
    }
    // stage B: 16x64, one float4 per thread
    {
      int k = t >> 4, n4 = (t & 15) * 4;
      float4 v = *reinterpret_cast<const float4*>(B + (size_t)(k0 + k) * ldb + col0 + n4);
      *reinterpret_cast<float4*>(&Bs[k * BN + n4]) = v;
    }
    __syncthreads();
#pragma unroll
    for (int kk = 0; kk < BK; ++kk) {
      float4 a0 = *reinterpret_cast<const float4*>(&As[kk * AS_STRIDE + ty * 8]);
      float4 a1 = *reinterpret_cast<const float4*>(&As[kk * AS_STRIDE + ty * 8 + 4]);
      float4 b0 = *reinterpret_cast<const float4*>(&Bs[kk * BN + tx * 4]);
      const float av[8] = {a0.x, a0.y, a0.z, a0.w, a1.x, a1.y, a1.z, a1.w};
      const float bw[4] = {b0.x, b0.y, b0.z, b0.w};
#pragma unroll
      for (int i = 0; i < 8; ++i)
#pragma unroll
        for (int j = 0; j < 4; ++j)
          acc[i][j] = fmaf(av[i], bw[j], acc[i][j]);
    }
  }

#pragma unroll
  for (int i = 0; i < 8; ++i) {
    int row = row0 + ty * 8 + i;
    if (row < M) {
      float4 o = make_float4(acc[i][0], acc[i][1], acc[i][2], acc[i][3]);
      if (bias) {
        o.x += bias[col0 + tx * 4 + 0]; o.y += bias[col0 + tx * 4 + 1];
        o.z += bias[col0 + tx * 4 + 2]; o.w += bias[col0 + tx * 4 + 3];
      }
      *reinterpret_cast<float4*>(C + (size_t)row * ldc + col0 + tx * 4) = o;
    }
  }
}

// ---------------- CSR build (by dst) ----------------
__global__ __launch_bounds__(256) void histo_kernel(
    const int* __restrict__ dst, int* __restrict__ deg, int E)
{
  int e = blockIdx.x * 256 + threadIdx.x;
  if (e < E) atomicAdd(&deg[dst[e]], 1);
}

__global__ __launch_bounds__(256) void scan_partial(
    const int* __restrict__ deg, int* __restrict__ incl, int* __restrict__ bsum, int N)
{
  __shared__ int s[256];
  int t = threadIdx.x;
  int n = blockIdx.x * 256 + t;
  int v = (n < N) ? deg[n] : 0;
  s[t] = v;
  __syncthreads();
#pragma unroll
  for (int o = 1; o < 256; o <<= 1) {
    int u = (t >= o) ? s[t - o] : 0;
    __syncthreads();
    s[t] += u;
    __syncthreads();
  }
  if (n < N) incl[n] = s[t];
  if (t == 255) bsum[blockIdx.x] = s[255];
}

__global__ __launch_bounds__(256) void scan_sums(int* __restrict__ bsum, int nb)
{
  __shared__ int s[256];
  int t = threadIdx.x;
  int v = (t < nb) ? bsum[t] : 0;
  s[t] = v;
  __syncthreads();
#pragma unroll
  for (int o = 1; o < 256; o <<= 1) {
    int u = (t >= o) ? s[t - o] : 0;
    __syncthreads();
    s[t] += u;
    __syncthreads();
  }
  if (t < nb) bsum[t] = s[t] - v;  // exclusive
}

__global__ __launch_bounds__(256) void scan_add(
    const int* __restrict__ incl, const int* __restrict__ deg,
    const int* __restrict__ bsum, int* __restrict__ off, int N, int E)
{
  int n = blockIdx.x * 256 + threadIdx.x;
  if (n < N) off[n] = incl[n] - deg[n] + bsum[n >> 8];
  if (n == 0) off[N] = E;
}

__global__ __launch_bounds__(256) void fill_kernel(
    const int* __restrict__ src, const int* __restrict__ dst,
    const int* __restrict__ et, const int* __restrict__ off,
    int* __restrict__ cursor, int* __restrict__ psrc, int* __restrict__ prel, int E)
{
  int e = blockIdx.x * 256 + threadIdx.x;
  if (e >= E) return;
  int d = dst[e];
  int pos = atomicAdd(&cursor[d], 1);
  int idx = off[d] + pos;
  psrc[idx] = src[e];
  prel[idx] = et[e];
}

// ---------------- aggregation: out[n] += sum over incoming edges of y[src, rel, :] ----------------
__global__ __launch_bounds__(256) void aggregate_kernel(
    const int* __restrict__ off, const int* __restrict__ psrc,
    const int* __restrict__ prel, const float* __restrict__ y,
    float* __restrict__ out, int N)
{
  int n = blockIdx.x * 4 + (threadIdx.x >> 6);
  if (n >= N) return;
  int lane = threadIdx.x & 63;
  int i0 = off[n], i1 = off[n + 1];
  float* o = out + (size_t)n * GDIM + lane * 4;
  float4 acc = *reinterpret_cast<const float4*>(o);  // self-loop result already there
  for (int i = i0; i < i1; ++i) {
    int s = psrc[i], r = prel[i];
    float4 v = *reinterpret_cast<const float4*>(y + (size_t)s * (3 * GDIM) + r * GDIM + lane * 4);
    acc.x += v.x; acc.y += v.y; acc.z += v.z; acc.w += v.w;
  }
  *reinterpret_cast<float4*>(o) = acc;
}

// ---------------- mean-pool (with relu on read) ----------------
__global__ __launch_bounds__(256) void pool_kernel(
    const float* __restrict__ x, const int* __restrict__ bv,
    float* __restrict__ hg, float* __restrict__ cnt, int N)
{
  __shared__ int sbv[128];
  int n0 = blockIdx.x * 128;
  int t = threadIdx.x;
  int nmax = min(128, N - n0);
  if (t < nmax) sbv[t] = bv[n0 + t];
  __syncthreads();
  float run = 0.f;
  int cur = sbv[0];
  for (int i = 0; i < nmax; ++i) {
    int b = sbv[i];
    if (b != cur) { atomicAdd(&hg[cur * GDIM + t], run); run = 0.f; cur = b; }
    run += fmaxf(x[(size_t)(n0 + i) * GDIM + t], 0.f);
  }
  atomicAdd(&hg[cur * GDIM + t], run);
  if (t == 0) {
    float c = 0.f; int cb = sbv[0];
    for (int i = 0; i < nmax; ++i) {
      int b = sbv[i];
      if (b != cb) { atomicAdd(&cnt[cb], c); c = 0.f; cb = b; }
      c += 1.f;
    }
    atomicAdd(&cnt[cb], c);
  }
}

// ---------------- small dense layers: split-K partials + epilogues ----------------
// partial[ks][b][j] = sum over k-chunk ks of X[b,k] * W[k,j]
__global__ __launch_bounds__(256) void smallgemm_partial(
    const float* __restrict__ X, const float* __restrict__ W,
    float* __restrict__ partial, int K, int Ncols, int KC)
{
  int j  = blockIdx.x * 256 + threadIdx.x;
  int b  = blockIdx.y;
  int ks = blockIdx.z;
  if (j >= Ncols) return;
  int k0 = ks * KC, k1 = min(K, k0 + KC);
  const float* xr = X + (size_t)b * K;
  float s0 = 0.f, s1 = 0.f, s2 = 0.f, s3 = 0.f;
  int k = k0;
  for (; k + 4 <= k1; k += 4) {
    s0 = fmaf(xr[k + 0], W[(size_t)(k + 0) * Ncols + j], s0);
    s1 = fmaf(xr[k + 1], W[(size_t)(k + 1) * Ncols + j], s1);
    s2 = fmaf(xr[k + 2], W[(size_t)(k + 2) * Ncols + j], s2);
    s3 = fmaf(xr[k + 3], W[(size_t)(k + 3) * Ncols + j], s3);
  }
  for (; k < k1; ++k) s0 = fmaf(xr[k], W[(size_t)k * Ncols + j], s0);
  partial[((size_t)ks * gridDim.y + b) * Ncols + j] = (s0 + s1) + (s2 + s3);
}

// out[b][j] = act(sum_ks partial + bias); optional second copy to out2[b*ld2 + off2 + j]
__global__ __launch_bounds__(256) void ep_sum(
    const float* __restrict__ partial, const float* __restrict__ bias,
    float* __restrict__ out, float* __restrict__ out2,
    int Ncols, int KS, int relu, int ld2, int off2)
{
  int j = blockIdx.x * 256 + threadIdx.x;
  int b = blockIdx.y;
  if (j >= Ncols) return;
  float s = bias ? bias[j] : 0.f;
  for (int ks = 0; ks < KS; ++ks)
    s += partial[((size_t)ks * gridDim.y + b) * Ncols + j];
  if (relu) s = fmaxf(s, 0.f);
  out[(size_t)b * Ncols + j] = s;
  if (out2) out2[(size_t)b * ld2 + off2 + j] = s;
}

// gate epilogue: g = sigmoid(sum + gb); f = g*h + (1-g)*hgp   (Ncols = 512)
__global__ __launch_bounds__(256) void ep_gate(
    const float* __restrict__ partial, const float* __restrict__ gb,
    const float* __restrict__ h, const float* __restrict__ hgp,
    float* __restrict__ f, int KS)
{
  int j = blockIdx.x * 256 + threadIdx.x;  // < 512
  int b = blockIdx.y;
  float s = gb[j];
  for (int ks = 0; ks < KS; ++ks)
    s += partial[((size_t)ks * gridDim.y + b) * HDIM + j];
  float g = 1.f / (1.f + expf(-s));
  f[(size_t)b * HDIM + j] = g * h[(size_t)b * HDIM + j] + (1.f - g) * hgp[(size_t)b * HDIM + j];
}

// hgm[b][t] = hg[b][t] / max(cnt[b], 1)
__global__ __launch_bounds__(256) void norm_kernel(
    const float* __restrict__ hg, const float* __restrict__ cnt, float* __restrict__ hgm)
{
  int b = blockIdx.x, t = threadIdx.x;  // 256 = GDIM
  float inv = 1.f / fmaxf(cnt[b], 1.f);
  hgm[(size_t)b * GDIM + t] = hg[(size_t)b * GDIM + t] * inv;
}

// final classifier layer: out[b][0..1] = z[b,:] @ c2_w + c2_b   (K = 256)
__global__ __launch_bounds__(256) void c2_kernel(
    const float* __restrict__ z, const float* __restrict__ w,
    const float* __restrict__ bias, float* __restrict__ out)
{
  __shared__ float r0[256], r1[256];
  int b = blockIdx.x, t = threadIdx.x;
  float zv = z[(size_t)b * 256 + t];
  r0[t] = zv * w[t * 2 + 0];
  r1[t] = zv * w[t * 2 + 1];
  __syncthreads();
  for (int o = 128; o > 0; o >>= 1) {
    if (t < o) { r0[t] += r0[t + o]; r1[t] += r1[t + o]; }
    __syncthreads();
  }
  if (t == 0) {
    out[b * 2 + 0] = r0[0] + bias[0];
    out[b * 2 + 1] = r1[0] + bias[1];
  }
}

extern "C" void kernel_launch(void* const* d_in, const int* in_sizes, int n_in,
                              void* d_out, int out_size, void* d_ws, size_t ws_size,
                              hipStream_t stream)
{
  const float* cls     = (const float*)d_in[0];
  const float* nf      = (const float*)d_in[1];
  const int*   ei      = (const int*)d_in[2];
  const int*   et      = (const int*)d_in[3];
  const int*   bv      = (const int*)d_in[4];
  const float* node_w  = (const float*)d_in[5];
  const float* node_b  = (const float*)d_in[6];
  const float* rel_w   = (const float*)d_in[7];
  const float* self_w  = (const float*)d_in[8];
  const float* self_b  = (const float*)d_in[9];
  const float* text_w  = (const float*)d_in[10];
  const float* text_b  = (const float*)d_in[11];
  const float* graph_w = (const float*)d_in[12];
  const float* graph_b = (const float*)d_in[13];
  const float* gate_w  = (const float*)d_in[14];
  const float* gate_b  = (const float*)d_in[15];
  const float* c1_w    = (const float*)d_in[16];
  const float* c1_b    = (const float*)d_in[17];
  const float* c2_w    = (const float*)d_in[18];
  const float* c2_b    = (const float*)d_in[19];

  const int Bsz = in_sizes[0] / 768;   // 64
  const int Nn  = in_sizes[1] / NF;    // 50000
  const int E   = in_sizes[3];         // 300000

  const int* src = ei;
  const int* dst = ei + E;

  // ---------------- workspace layout ----------------
  float* ws = (float*)d_ws;
  size_t off_f = 0;
  float* x0  = ws + off_f; off_f += (size_t)Nn * GDIM;       // node states (ping)
  float* x1  = ws + off_f; off_f += (size_t)Nn * GDIM;       // node states (pong)
  float* y   = ws + off_f; off_f += (size_t)Nn * 3 * GDIM;   // per-relation transforms [N][3][256]
  float* h   = ws + off_f; off_f += (size_t)Bsz * HDIM;
  float* hg  = ws + off_f; off_f += (size_t)Bsz * GDIM;      // pooled sums
  float* cnt = ws + off_f; off_f += (size_t)Bsz;
  float* hgp = ws + off_f; off_f += (size_t)Bsz * HDIM;
  float* f   = ws + off_f; off_f += (size_t)Bsz * HDIM;
  float* z   = ws + off_f; off_f += (size_t)Bsz * (HDIM/2);
  float* hgm = ws + off_f; off_f += (size_t)Bsz * GDIM;      // normalized pooled
  float* hcat= ws + off_f; off_f += (size_t)Bsz * 2 * HDIM;  // [h, hgp]
  float* pp  = ws + off_f; off_f += (size_t)8 * Bsz * HDIM;  // split-K partials (max 8 chunks)
  // persistent CSR
  int* csr_off = (int*)(ws + off_f);          // N+1
  int* psrc    = csr_off + (Nn + 1);          // E
  int* prel    = psrc + E;                    // E
  // transient CSR-build scratch overlaid on x1 (x1 first written AFTER build)
  int* deg    = (int*)x1;       // N
  int* incl   = deg + Nn;       // N
  int* cursor = incl + Nn;      // N
  int* bsum   = cursor + Nn;    // 256

  dim3 blk(256);
  const int nbN = (Nn + 255) / 256;
  const int nbE = (E + 255) / 256;
  const int KC  = 128;

  // ---------------- CSR build (once; reused by both layers) ----------------
  hipMemsetAsync(deg, 0, (size_t)(3 * Nn + 256) * sizeof(int), stream);
  histo_kernel<<<nbE, blk, 0, stream>>>(dst, deg, E);
  scan_partial<<<nbN, blk, 0, stream>>>(deg, incl, bsum, Nn);
  scan_sums<<<1, blk, 0, stream>>>(bsum, nbN);
  scan_add<<<nbN, blk, 0, stream>>>(incl, deg, bsum, csr_off, Nn, E);
  fill_kernel<<<nbE, blk, 0, stream>>>(src, dst, et, csr_off, cursor, psrc, prel, E);

  // zero pooled accumulators (hg, cnt contiguous)
  hipMemsetAsync(hg, 0, (size_t)(Bsz * GDIM + Bsz) * sizeof(float), stream);

  // text projection: h = cls @ text_w + text_b  (also h -> hcat[:, :512])
  smallgemm_partial<<<dim3(2, Bsz, 6), blk, 0, stream>>>(cls, text_w, pp, 768, HDIM, KC);
  ep_sum<<<dim3(2, Bsz), blk, 0, stream>>>(pp, text_b, h, hcat, HDIM, 6, 0, 2 * HDIM, 0);

  // node projection: x0 = nf @ node_w + node_b
  dim3 ggrid((Nn + BM - 1) / BM, 4);
  gemm_f32<<<ggrid, blk, 0, stream>>>(nf, node_w, node_b, x0, Nn, NF, GDIM, GDIM, 0);

  // RGCN layers
  for (int l = 0; l < 2; ++l) {
    const float* A = l ? x1 : x0;
    float* outb    = l ? x0 : x1;
    int relu_a     = l ? 1 : 0;
    gemm_f32<<<ggrid, blk, 0, stream>>>(A, self_w + (size_t)l * GDIM * GDIM,
                                        self_b + (size_t)l * GDIM, outb,
                                        Nn, GDIM, GDIM, GDIM, relu_a);
    for (int r = 0; r < 3; ++r)
      gemm_f32<<<ggrid, blk, 0, stream>>>(A, rel_w + ((size_t)l * 3 + r) * GDIM * GDIM,
                                          nullptr, y + (size_t)r * GDIM,
                                          Nn, GDIM, GDIM, 3 * GDIM, relu_a);
    aggregate_kernel<<<dim3((Nn + 3) / 4), blk, 0, stream>>>(csr_off, psrc, prel, y, outb, Nn);
  }

  // mean pool (applies final relu on read)
  pool_kernel<<<dim3((Nn + 127) / 128), blk, 0, stream>>>(x0, bv, hg, cnt, Nn);

  // normalize pooled sums
  norm_kernel<<<dim3(Bsz), blk, 0, stream>>>(hg, cnt, hgm);

  // graph projection: hgp = hgm @ graph_w + graph_b  (also -> hcat[:, 512:])
  smallgemm_partial<<<dim3(2, Bsz, 2), blk, 0, stream>>>(hgm, graph_w, pp, GDIM, HDIM, KC);
  ep_sum<<<dim3(2, Bsz), blk, 0, stream>>>(pp, graph_b, hgp, hcat, HDIM, 2, 0, 2 * HDIM, HDIM);

  // gated fusion: f = sigmoid(hcat @ gate_w + gate_b) * h + (1-g) * hgp
  smallgemm_partial<<<dim3(2, Bsz, 8), blk, 0, stream>>>(hcat, gate_w, pp, 2 * HDIM, HDIM, KC);
  ep_gate<<<dim3(2, Bsz), blk, 0, stream>>>(pp, gate_b, h, hgp, f, 8);

  // classifier layer 1: z = relu(f @ c1_w + c1_b)
  smallgemm_partial<<<dim3(1, Bsz, 4), blk, 0, stream>>>(f, c1_w, pp, HDIM, HDIM / 2, KC);
  ep_sum<<<dim3(1, Bsz), blk, 0, stream>>>(pp, c1_b, z, nullptr, HDIM / 2, 4, 1, 0, 0);

  // classifier layer 2: logits
  c2_kernel<<<dim3(Bsz), blk, 0, stream>>>(z, c2_w, c2_b, (float*)d_out);
}

// Round 5
// 582.598 us; speedup vs baseline: 6.0055x; 2.0508x over previous
//
#include <hip/hip_runtime.h>
#include <hip/hip_bf16.h>
#include <cstdint>
#include <cstddef>

// Problem constants (VulnDetector): B=64, N=50000, E=300000, NF=128, G=256, H=512, R=3, L=2
constexpr int GDIM = 256;   // graph hidden
constexpr int HDIM = 512;   // fusion hidden
constexpr int NF   = 128;   // node features

typedef __attribute__((ext_vector_type(8))) short bf16x8;
typedef __attribute__((ext_vector_type(4))) float f32x4;

__device__ __forceinline__ unsigned short f2bf(float x) {
  union { float f; unsigned int u; } v; v.f = x;
  unsigned int r = v.u + 0x7FFF + ((v.u >> 16) & 1);   // RNE
  return (unsigned short)(r >> 16);
}
__device__ __forceinline__ float bf2f(unsigned int h) {
  union { unsigned int u; float f; } v; v.u = h << 16; return v.f;
}

__device__ __forceinline__ void gload16(const void* g, void* l) {
  __builtin_amdgcn_global_load_lds(
      (const __attribute__((address_space(1))) unsigned int*)g,
      (__attribute__((address_space(3))) unsigned int*)l, 16, 0, 0);
}

// ---------------- bf16 MFMA GEMM ----------------
// C[M, NOUT] = A[M,K]bf16 @ Wt[NOUT,K]bf16^T, fp32 accum.
// Grid (ceil(M/128), NOUT/128), 256 thr = 4 waves (2x2, 64x64 each).
// Col-blocks < nself_blocks -> out0 fp32 [M][256] (+bias);
// else -> out1 bf16 [M][768] at col-256.
__global__ __launch_bounds__(256) void mfma_gemm(
    const unsigned short* __restrict__ A, const unsigned short* __restrict__ Wt,
    const float* __restrict__ bias, float* __restrict__ out0,
    unsigned short* __restrict__ out1, int M, int K, int nself_blocks)
{
  __shared__ __align__(16) unsigned short lds[2 * 128 * 64];  // A tile | B tile (16 KB each)
  char* ldsb = (char*)lds;
  const int t    = threadIdx.x;
  const int lane = t & 63;
  const int w    = t >> 6;
  const int row0 = blockIdx.x * 128;
  const int n0   = blockIdx.y * 128;
  const int wr   = w >> 1, wc = w & 1;

  f32x4 acc[4][4] = {};

  // staging decode: issue i, wave w covers LDS bytes [(i*4+w)*1024, +1024)
  // linear L = base + lane*16 -> row = L>>7, slot = (L>>4)&7 (row stride 128 B = 64 bf16)
  const int srow  = lane >> 3;
  const int sslot = lane & 7;

  for (int k0 = 0; k0 < K; k0 += 64) {
    __syncthreads();  // previous compute done before overwrite
#pragma unroll
    for (int i = 0; i < 4; ++i) {
      int row  = (i * 4 + w) * 8 + srow;
      int slot = sslot ^ (row & 7);            // pre-swizzled global source (m173 pattern)
      int grA  = min(row0 + row, M - 1);
      gload16(A  + (size_t)grA        * K + k0 + slot * 8, ldsb +         (i * 4 + w) * 1024);
      gload16(Wt + (size_t)(n0 + row) * K + k0 + slot * 8, ldsb + 16384 + (i * 4 + w) * 1024);
    }
    __syncthreads();  // implicit vmcnt(0) drain covers global_load_lds

#pragma unroll
    for (int kc = 0; kc < 2; ++kc) {
      bf16x8 af[4], bfr[4];
#pragma unroll
      for (int m = 0; m < 4; ++m) {
        int row  = wr * 64 + m * 16 + (lane & 15);
        int slot = (kc * 4 + (lane >> 4)) ^ (row & 7);   // swizzled read
        af[m] = *(const bf16x8*)(ldsb + row * 128 + slot * 16);
      }
#pragma unroll
      for (int n = 0; n < 4; ++n) {
        int row  = wc * 64 + n * 16 + (lane & 15);
        int slot = (kc * 4 + (lane >> 4)) ^ (row & 7);
        bfr[n] = *(const bf16x8*)(ldsb + 16384 + row * 128 + slot * 16);
      }
#pragma unroll
      for (int m = 0; m < 4; ++m)
#pragma unroll
        for (int n = 0; n < 4; ++n)
          acc[m][n] = __builtin_amdgcn_mfma_f32_16x16x32_bf16(af[m], bfr[n], acc[m][n], 0, 0, 0);
    }
  }

  // epilogue: C/D layout col=lane&15, row=(lane>>4)*4+reg
  const bool toself = (int)blockIdx.y < nself_blocks;
#pragma unroll
  for (int m = 0; m < 4; ++m) {
    int rbase = row0 + wr * 64 + m * 16 + (lane >> 4) * 4;
#pragma unroll
    for (int n = 0; n < 4; ++n) {
      int c = n0 + wc * 64 + n * 16 + (lane & 15);
#pragma unroll
      for (int i = 0; i < 4; ++i) {
        int r = rbase + i;
        if (r < M) {
          float v = acc[m][n][i];
          if (toself) out0[(size_t)r * 256 + c] = v + bias[c];
          else        out1[(size_t)r * 768 + (c - 256)] = f2bf(v);
        }
      }
    }
  }
}

// ---------------- converts / weight prep ----------------
// xb = bf16(relu?(x)), 4 elems/thread
__global__ __launch_bounds__(256) void convert_bf16(
    const float* __restrict__ x, unsigned short* __restrict__ xb, int n, int relu)
{
  int i = (blockIdx.x * 256 + threadIdx.x) * 4;
  if (i >= n) return;
  float4 v = *(const float4*)(x + i);
  if (relu) {
    v.x = fmaxf(v.x, 0.f); v.y = fmaxf(v.y, 0.f);
    v.z = fmaxf(v.z, 0.f); v.w = fmaxf(v.w, 0.f);
  }
  ushort4 o; o.x = f2bf(v.x); o.y = f2bf(v.y); o.z = f2bf(v.z); o.w = f2bf(v.w);
  *(ushort4*)(xb + i) = o;
}

// wt[n][k] = bf16(w[k][n]); w row-major [K][N]
__global__ __launch_bounds__(256) void prep_wt(
    const float* __restrict__ w, unsigned short* __restrict__ wt, int K, int N)
{
  int idx = blockIdx.x * 256 + threadIdx.x;
  if (idx >= N * K) return;
  int nn = idx / K, kk = idx - nn * K;
  wt[idx] = f2bf(w[(size_t)kk * N + nn]);
}

// ---------------- CSR build (by dst) ----------------
__global__ __launch_bounds__(256) void histo_kernel(
    const int* __restrict__ dst, int* __restrict__ deg, int E)
{
  int e = blockIdx.x * 256 + threadIdx.x;
  if (e < E) atomicAdd(&deg[dst[e]], 1);
}

__global__ __launch_bounds__(256) void scan_partial(
    const int* __restrict__ deg, int* __restrict__ incl, int* __restrict__ bsum, int N)
{
  __shared__ int s[256];
  int t = threadIdx.x;
  int n = blockIdx.x * 256 + t;
  int v = (n < N) ? deg[n] : 0;
  s[t] = v;
  __syncthreads();
#pragma unroll
  for (int o = 1; o < 256; o <<= 1) {
    int u = (t >= o) ? s[t - o] : 0;
    __syncthreads();
    s[t] += u;
    __syncthreads();
  }
  if (n < N) incl[n] = s[t];
  if (t == 255) bsum[blockIdx.x] = s[255];
}

__global__ __launch_bounds__(256) void scan_sums(int* __restrict__ bsum, int nb)
{
  __shared__ int s[256];
  int t = threadIdx.x;
  int v = (t < nb) ? bsum[t] : 0;
  s[t] = v;
  __syncthreads();
#pragma unroll
  for (int o = 1; o < 256; o <<= 1) {
    int u = (t >= o) ? s[t - o] : 0;
    __syncthreads();
    s[t] += u;
    __syncthreads();
  }
  if (t < nb) bsum[t] = s[t] - v;  // exclusive
}

__global__ __launch_bounds__(256) void scan_add(
    const int* __restrict__ incl, const int* __restrict__ deg,
    const int* __restrict__ bsum, int* __restrict__ off, int N, int E)
{
  int n = blockIdx.x * 256 + threadIdx.x;
  if (n < N) off[n] = incl[n] - deg[n] + bsum[n >> 8];
  if (n == 0) off[N] = E;
}

__global__ __launch_bounds__(256) void fill_kernel(
    const int* __restrict__ src, const int* __restrict__ dst,
    const int* __restrict__ et, const int* __restrict__ off,
    int* __restrict__ cursor, int* __restrict__ psrc, int* __restrict__ prel, int E)
{
  int e = blockIdx.x * 256 + threadIdx.x;
  if (e >= E) return;
  int d = dst[e];
  int pos = atomicAdd(&cursor[d], 1);
  int idx = off[d] + pos;
  psrc[idx] = src[e];
  prel[idx] = et[e];
}

// ---------------- aggregation: out[n] += sum of yb[src, rel, :] (bf16 gather) ----------------
__global__ __launch_bounds__(256) void aggregate_kernel(
    const int* __restrict__ off, const int* __restrict__ psrc,
    const int* __restrict__ prel, const unsigned short* __restrict__ yb,
    float* __restrict__ out, int N)
{
  int n = blockIdx.x * 4 + (threadIdx.x >> 6);
  if (n >= N) return;
  int lane = threadIdx.x & 63;
  int i0 = off[n], i1 = off[n + 1];
  float* o = out + (size_t)n * GDIM + lane * 4;
  float4 acc = *(const float4*)o;  // self-loop result already there
  for (int i = i0; i < i1; ++i) {
    int s = psrc[i], r = prel[i];
    uint2 u = *(const uint2*)(yb + (size_t)s * 768 + r * 256 + lane * 4);
    acc.x += bf2f(u.x & 0xFFFF);
    acc.y += bf2f(u.x >> 16);
    acc.z += bf2f(u.y & 0xFFFF);
    acc.w += bf2f(u.y >> 16);
  }
  *(float4*)o = acc;
}

// ---------------- mean-pool (with relu on read) ----------------
__global__ __launch_bounds__(256) void pool_kernel(
    const float* __restrict__ x, const int* __restrict__ bv,
    float* __restrict__ hg, float* __restrict__ cnt, int N)
{
  __shared__ int sbv[128];
  int n0 = blockIdx.x * 128;
  int t = threadIdx.x;
  int nmax = min(128, N - n0);
  if (t < nmax) sbv[t] = bv[n0 + t];
  __syncthreads();
  float run = 0.f;
  int cur = sbv[0];
  for (int i = 0; i < nmax; ++i) {
    int b = sbv[i];
    if (b != cur) { atomicAdd(&hg[cur * GDIM + t], run); run = 0.f; cur = b; }
    run += fmaxf(x[(size_t)(n0 + i) * GDIM + t], 0.f);
  }
  atomicAdd(&hg[cur * GDIM + t], run);
  if (t == 0) {
    float c = 0.f; int cb = sbv[0];
    for (int i = 0; i < nmax; ++i) {
      int b = sbv[i];
      if (b != cb) { atomicAdd(&cnt[cb], c); c = 0.f; cb = b; }
      c += 1.f;
    }
    atomicAdd(&cnt[cb], c);
  }
}

// ---------------- small dense layers: split-K partials + epilogues ----------------
__global__ __launch_bounds__(256) void smallgemm_partial(
    const float* __restrict__ X, const float* __restrict__ W,
    float* __restrict__ partial, int K, int Ncols, int KC)
{
  int j  = blockIdx.x * 256 + threadIdx.x;
  int b  = blockIdx.y;
  int ks = blockIdx.z;
  if (j >= Ncols) return;
  int k0 = ks * KC, k1 = min(K, k0 + KC);
  const float* xr = X + (size_t)b * K;
  float s0 = 0.f, s1 = 0.f, s2 = 0.f, s3 = 0.f;
  int k = k0;
  for (; k + 4 <= k1; k += 4) {
    s0 = fmaf(xr[k + 0], W[(size_t)(k + 0) * Ncols + j], s0);
    s1 = fmaf(xr[k + 1], W[(size_t)(k + 1) * Ncols + j], s1);
    s2 = fmaf(xr[k + 2], W[(size_t)(k + 2) * Ncols + j], s2);
    s3 = fmaf(xr[k + 3], W[(size_t)(k + 3) * Ncols + j], s3);
  }
  for (; k < k1; ++k) s0 = fmaf(xr[k], W[(size_t)k * Ncols + j], s0);
  partial[((size_t)ks * gridDim.y + b) * Ncols + j] = (s0 + s1) + (s2 + s3);
}

__global__ __launch_bounds__(256) void ep_sum(
    const float* __restrict__ partial, const float* __restrict__ bias,
    float* __restrict__ out, float* __restrict__ out2,
    int Ncols, int KS, int relu, int ld2, int off2)
{
  int j = blockIdx.x * 256 + threadIdx.x;
  int b = blockIdx.y;
  if (j >= Ncols) return;
  float s = bias ? bias[j] : 0.f;
  for (int ks = 0; ks < KS; ++ks)
    s += partial[((size_t)ks * gridDim.y + b) * Ncols + j];
  if (relu) s = fmaxf(s, 0.f);
  out[(size_t)b * Ncols + j] = s;
  if (out2) out2[(size_t)b * ld2 + off2 + j] = s;
}

__global__ __launch_bounds__(256) void ep_gate(
    const float* __restrict__ partial, const float* __restrict__ gb,
    const float* __restrict__ h, const float* __restrict__ hgp,
    float* __restrict__ f, int KS)
{
  int j = blockIdx.x * 256 + threadIdx.x;  // < 512
  int b = blockIdx.y;
  float s = gb[j];
  for (int ks = 0; ks < KS; ++ks)
    s += partial[((size_t)ks * gridDim.y + b) * HDIM + j];
  float g = 1.f / (1.f + expf(-s));
  f[(size_t)b * HDIM + j] = g * h[(size_t)b * HDIM + j] + (1.f - g) * hgp[(size_t)b * HDIM + j];
}

__global__ __launch_bounds__(256) void norm_kernel(
    const float* __restrict__ hg, const float* __restrict__ cnt, float* __restrict__ hgm)
{
  int b = blockIdx.x, t = threadIdx.x;  // 256 = GDIM
  float inv = 1.f / fmaxf(cnt[b], 1.f);
  hgm[(size_t)b * GDIM + t] = hg[(size_t)b * GDIM + t] * inv;
}

__global__ __launch_bounds__(256) void c2_kernel(
    const float* __restrict__ z, const float* __restrict__ w,
    const float* __restrict__ bias, float* __restrict__ out)
{
  __shared__ float r0[256], r1[256];
  int b = blockIdx.x, t = threadIdx.x;
  float zv = z[(size_t)b * 256 + t];
  r0[t] = zv * w[t * 2 + 0];
  r1[t] = zv * w[t * 2 + 1];
  __syncthreads();
  for (int o = 128; o > 0; o >>= 1) {
    if (t < o) { r0[t] += r0[t + o]; r1[t] += r1[t + o]; }
    __syncthreads();
  }
  if (t == 0) {
    out[b * 2 + 0] = r0[0] + bias[0];
    out[b * 2 + 1] = r1[0] + bias[1];
  }
}

extern "C" void kernel_launch(void* const* d_in, const int* in_sizes, int n_in,
                              void* d_out, int out_size, void* d_ws, size_t ws_size,
                              hipStream_t stream)
{
  const float* cls     = (const float*)d_in[0];
  const float* nf      = (const float*)d_in[1];
  const int*   ei      = (const int*)d_in[2];
  const int*   et      = (const int*)d_in[3];
  const int*   bv      = (const int*)d_in[4];
  const float* node_w  = (const float*)d_in[5];
  const float* node_b  = (const float*)d_in[6];
  const float* rel_w   = (const float*)d_in[7];
  const float* self_w  = (const float*)d_in[8];
  const float* self_b  = (const float*)d_in[9];
  const float* text_w  = (const float*)d_in[10];
  const float* text_b  = (const float*)d_in[11];
  const float* graph_w = (const float*)d_in[12];
  const float* graph_b = (const float*)d_in[13];
  const float* gate_w  = (const float*)d_in[14];
  const float* gate_b  = (const float*)d_in[15];
  const float* c1_w    = (const float*)d_in[16];
  const float* c1_b    = (const float*)d_in[17];
  const float* c2_w    = (const float*)d_in[18];
  const float* c2_b    = (const float*)d_in[19];

  const int Bsz = in_sizes[0] / 768;   // 64
  const int Nn  = in_sizes[1] / NF;    // 50000
  const int E   = in_sizes[3];         // 300000

  const int* src = ei;
  const int* dst = ei + E;

  // ---------------- workspace layout ----------------
  float* ws = (float*)d_ws;
  size_t off_f = 0;
  float* x0  = ws + off_f; off_f += (size_t)Nn * GDIM;       // node states fp32 (ping)
  float* x1  = ws + off_f; off_f += (size_t)Nn * GDIM;       // node states fp32 (pong)
  unsigned short* yb = (unsigned short*)(ws + off_f);        // y bf16 [N][768]
  off_f += ((size_t)Nn * 768 + 1) / 2;
  unsigned short* xb = (unsigned short*)(ws + off_f);        // A bf16 [N][256]
  off_f += ((size_t)Nn * GDIM + 1) / 2;
  float* h   = ws + off_f; off_f += (size_t)Bsz * HDIM;
  float* hg  = ws + off_f; off_f += (size_t)Bsz * GDIM;
  float* cnt = ws + off_f; off_f += (size_t)Bsz;
  float* hgp = ws + off_f; off_f += (size_t)Bsz * HDIM;
  float* f   = ws + off_f; off_f += (size_t)Bsz * HDIM;
  float* z   = ws + off_f; off_f += (size_t)Bsz * (HDIM/2);
  float* hgm = ws + off_f; off_f += (size_t)Bsz * GDIM;
  float* hcat= ws + off_f; off_f += (size_t)Bsz * 2 * HDIM;
  float* pp  = ws + off_f; off_f += (size_t)8 * Bsz * HDIM;
  unsigned short* wt_node = (unsigned short*)(ws + off_f); off_f += (GDIM * NF) / 2;
  unsigned short* wt_l0   = (unsigned short*)(ws + off_f); off_f += (4 * GDIM * GDIM) / 2;
  unsigned short* wt_l1   = (unsigned short*)(ws + off_f); off_f += (4 * GDIM * GDIM) / 2;
  // persistent CSR
  int* csr_off = (int*)(ws + off_f);          // N+1
  int* psrc    = csr_off + (Nn + 1);          // E
  int* prel    = psrc + E;                    // E
  // transient CSR-build scratch overlaid on x1 (x1 first written by layer-0 GEMM)
  int* deg    = (int*)x1;       // N
  int* incl   = deg + Nn;       // N
  int* cursor = incl + Nn;      // N
  int* bsum   = cursor + Nn;    // 256
  // nf bf16 overlaid on yb (consumed by node proj before y is first written)
  unsigned short* nfb = yb;

  dim3 blk(256);
  const int nbN = (Nn + 255) / 256;
  const int nbE = (E + 255) / 256;
  const int KC  = 128;

  // ---------------- CSR build (once; reused by both layers) ----------------
  hipMemsetAsync(deg, 0, (size_t)(3 * Nn + 256) * sizeof(int), stream);
  histo_kernel<<<nbE, blk, 0, stream>>>(dst, deg, E);
  scan_partial<<<nbN, blk, 0, stream>>>(deg, incl, bsum, Nn);
  scan_sums<<<1, blk, 0, stream>>>(bsum, nbN);
  scan_add<<<nbN, blk, 0, stream>>>(incl, deg, bsum, csr_off, Nn, E);
  fill_kernel<<<nbE, blk, 0, stream>>>(src, dst, et, csr_off, cursor, psrc, prel, E);

  // ---------------- weight prep (bf16, transposed to [N][K]) ----------------
  prep_wt<<<(GDIM * NF) / 256, blk, 0, stream>>>(node_w, wt_node, NF, GDIM);
  for (int l = 0; l < 2; ++l) {
    unsigned short* wt_l = l ? wt_l1 : wt_l0;
    prep_wt<<<(GDIM * GDIM) / 256, blk, 0, stream>>>(
        self_w + (size_t)l * GDIM * GDIM, wt_l, GDIM, GDIM);
    for (int r = 0; r < 3; ++r)
      prep_wt<<<(GDIM * GDIM) / 256, blk, 0, stream>>>(
          rel_w + ((size_t)l * 3 + r) * GDIM * GDIM, wt_l + (size_t)(1 + r) * GDIM * GDIM,
          GDIM, GDIM);
  }

  // zero pooled accumulators (hg, cnt contiguous)
  hipMemsetAsync(hg, 0, (size_t)(Bsz * GDIM + Bsz) * sizeof(float), stream);

  // text projection (split-K)
  smallgemm_partial<<<dim3(2, Bsz, 6), blk, 0, stream>>>(cls, text_w, pp, 768, HDIM, KC);
  ep_sum<<<dim3(2, Bsz), blk, 0, stream>>>(pp, text_b, h, hcat, HDIM, 6, 0, 2 * HDIM, 0);

  // node projection: x0 = nf @ node_w + node_b (bf16 MFMA)
  convert_bf16<<<(Nn * NF) / 4 / 256, blk, 0, stream>>>(nf, nfb, Nn * NF, 0);
  mfma_gemm<<<dim3((Nn + 127) / 128, 2), blk, 0, stream>>>(
      nfb, wt_node, node_b, x0, nullptr, Nn, NF, 2);

  // RGCN layers
  for (int l = 0; l < 2; ++l) {
    const float* Af = l ? x1 : x0;
    float* outb     = l ? x0 : x1;
    unsigned short* wt_l = l ? wt_l1 : wt_l0;
    // A -> bf16 (relu for layer 1 input)
    convert_bf16<<<(Nn * GDIM) / 4 / 256, blk, 0, stream>>>(Af, xb, Nn * GDIM, l ? 1 : 0);
    // fused self+rel GEMM: cols 0-255 -> outb (+self_b), 256-1023 -> yb
    mfma_gemm<<<dim3((Nn + 127) / 128, 8), blk, 0, stream>>>(
        xb, wt_l, self_b + (size_t)l * GDIM, outb, yb, Nn, GDIM, 2);
    // message passing via CSR gather (no atomics)
    aggregate_kernel<<<dim3((Nn + 3) / 4), blk, 0, stream>>>(csr_off, psrc, prel, yb, outb, Nn);
  }

  // mean pool (applies final relu on read)
  pool_kernel<<<dim3((Nn + 127) / 128), blk, 0, stream>>>(x0, bv, hg, cnt, Nn);

  // normalize pooled sums
  norm_kernel<<<dim3(Bsz), blk, 0, stream>>>(hg, cnt, hgm);

  // graph projection (also -> hcat[:, 512:])
  smallgemm_partial<<<dim3(2, Bsz, 2), blk, 0, stream>>>(hgm, graph_w, pp, GDIM, HDIM, KC);
  ep_sum<<<dim3(2, Bsz), blk, 0, stream>>>(pp, graph_b, hgp, hcat, HDIM, 2, 0, 2 * HDIM, HDIM);

  // gated fusion
  smallgemm_partial<<<dim3(2, Bsz, 8), blk, 0, stream>>>(hcat, gate_w, pp, 2 * HDIM, HDIM, KC);
  ep_gate<<<dim3(2, Bsz), blk, 0, stream>>>(pp, gate_b, h, hgp, f, 8);

  // classifier
  smallgemm_partial<<<dim3(1, Bsz, 4), blk, 0, stream>>>(f, c1_w, pp, HDIM, HDIM / 2, KC);
  ep_sum<<<dim3(1, Bsz), blk, 0, stream>>>(pp, c1_b, z, nullptr, HDIM / 2, 4, 1, 0, 0);
  c2_kernel<<<dim3(Bsz), blk, 0, stream>>>(z, c2_w, c2_b, (float*)d_out);
}

// Round 9
// 528.136 us; speedup vs baseline: 6.6248x; 1.1031x over previous
//
#include <hip/hip_runtime.h>
#include <hip/hip_bf16.h>
#include <cstdint>
#include <cstddef>

// Problem constants (VulnDetector): B=64, N=50000, E=300000, NF=128, G=256, H=512, R=3, L=2
constexpr int GDIM = 256;   // graph hidden
constexpr int HDIM = 512;   // fusion hidden
constexpr int NF   = 128;   // node features

typedef __attribute__((ext_vector_type(8))) short bf16x8;
typedef __attribute__((ext_vector_type(4))) float f32x4;

__device__ __forceinline__ unsigned short f2bf(float x) {
  union { float f; unsigned int u; } v; v.f = x;
  unsigned int r = v.u + 0x7FFF + ((v.u >> 16) & 1);   // RNE
  return (unsigned short)(r >> 16);
}
__device__ __forceinline__ float bf2f(unsigned int h) {
  union { unsigned int u; float f; } v; v.u = h << 16; return v.f;
}

__device__ __forceinline__ void gload16(const void* g, void* l) {
  __builtin_amdgcn_global_load_lds(
      (const __attribute__((address_space(1))) unsigned int*)g,
      (__attribute__((address_space(3))) unsigned int*)l, 16, 0, 0);
}

// ---------------- bf16 MFMA GEMM ----------------
// out[M][ldout]bf16 = A[M,K]bf16 @ Wt[NOUT,K]bf16^T; bias (fp32) added for cols < nbias.
// 1D grid = nrb*ncb; bijective XCD swizzle (m204) then col-fastest decode so all
// col-blocks of one row-panel run on the same XCD (A panel L2-resident).
__global__ __launch_bounds__(256) void mfma_gemm(
    const unsigned short* __restrict__ A, const unsigned short* __restrict__ Wt,
    const float* __restrict__ bias, unsigned short* __restrict__ out,
    int M, int K, int ldout, int nbias, int ncb)
{
  __shared__ __align__(16) unsigned short lds[2 * 128 * 64];  // A tile | B tile (16 KB each)
  char* ldsb = (char*)lds;
  const int nwg  = gridDim.x;
  const int orig = blockIdx.x;
  const int q = nwg >> 3, r = nwg & 7;
  const int xcd = orig & 7, sidx = orig >> 3;
  const int wgid = (xcd < r ? xcd * (q + 1) : r * (q + 1) + (xcd - r) * q) + sidx;
  const int row0 = (wgid / ncb) * 128;
  const int n0   = (wgid % ncb) * 128;

  const int t    = threadIdx.x;
  const int lane = t & 63;
  const int w    = t >> 6;
  const int wr   = w >> 1, wc = w & 1;

  f32x4 acc[4][4] = {};

  // staging: issue i, wave w covers LDS bytes [(i*4+w)*1024, +1024), row stride 128 B
  const int srow  = lane >> 3;
  const int sslot = lane & 7;

  for (int k0 = 0; k0 < K; k0 += 64) {
    __syncthreads();
#pragma unroll
    for (int i = 0; i < 4; ++i) {
      int row  = (i * 4 + w) * 8 + srow;
      int slot = sslot ^ (row & 7);            // pre-swizzled global source (m173 pattern)
      int grA  = min(row0 + row, M - 1);
      gload16(A  + (size_t)grA        * K + k0 + slot * 8, ldsb +         (i * 4 + w) * 1024);
      gload16(Wt + (size_t)(n0 + row) * K + k0 + slot * 8, ldsb + 16384 + (i * 4 + w) * 1024);
    }
    __syncthreads();  // implicit vmcnt(0) drain covers global_load_lds

#pragma unroll
    for (int kc = 0; kc < 2; ++kc) {
      bf16x8 af[4], bfr[4];
#pragma unroll
      for (int m = 0; m < 4; ++m) {
        int row  = wr * 64 + m * 16 + (lane & 15);
        int slot = (kc * 4 + (lane >> 4)) ^ (row & 7);   // swizzled read
        af[m] = *(const bf16x8*)(ldsb + row * 128 + slot * 16);
      }
#pragma unroll
      for (int n = 0; n < 4; ++n) {
        int row  = wc * 64 + n * 16 + (lane & 15);
        int slot = (kc * 4 + (lane >> 4)) ^ (row & 7);
        bfr[n] = *(const bf16x8*)(ldsb + 16384 + row * 128 + slot * 16);
      }
#pragma unroll
      for (int m = 0; m < 4; ++m)
#pragma unroll
        for (int n = 0; n < 4; ++n)
          acc[m][n] = __builtin_amdgcn_mfma_f32_16x16x32_bf16(af[m], bfr[n], acc[m][n], 0, 0, 0);
    }
  }

  // epilogue: C/D layout col=lane&15, row=(lane>>4)*4+reg; bf16 out (+bias cols < nbias)
#pragma unroll
  for (int m = 0; m < 4; ++m) {
    int rbase = row0 + wr * 64 + m * 16 + (lane >> 4) * 4;
#pragma unroll
    for (int n = 0; n < 4; ++n) {
      int c = n0 + wc * 64 + n * 16 + (lane & 15);
      float badd = (c < nbias) ? bias[c] : 0.f;
#pragma unroll
      for (int i = 0; i < 4; ++i) {
        int rr = rbase + i;
        if (rr < M) out[(size_t)rr * ldout + c] = f2bf(acc[m][n][i] + badd);
      }
    }
  }
}

// ---------------- converts / weight prep ----------------
__global__ __launch_bounds__(256) void convert_bf16(
    const float* __restrict__ x, unsigned short* __restrict__ xb, int n)
{
  int i = (blockIdx.x * 256 + threadIdx.x) * 4;
  if (i >= n) return;
  float4 v = *(const float4*)(x + i);
  ushort4 o; o.x = f2bf(v.x); o.y = f2bf(v.y); o.z = f2bf(v.z); o.w = f2bf(v.w);
  *(ushort4*)(xb + i) = o;
}

// all 9 weight transposes in one launch: node(256x128), then l0/l1 x {self,rel0,rel1,rel2}
__global__ __launch_bounds__(256) void prep_all(
    const float* __restrict__ node_w, const float* __restrict__ self_w,
    const float* __restrict__ rel_w, unsigned short* __restrict__ wt_node,
    unsigned short* __restrict__ wt_l0, unsigned short* __restrict__ wt_l1)
{
  int idx = blockIdx.x * 256 + threadIdx.x;
  if (idx < 256 * 128) {
    int nn = idx >> 7, kk = idx & 127;           // wt_node[n][k] = node_w[k][n]
    wt_node[idx] = f2bf(node_w[kk * 256 + nn]);
    return;
  }
  idx -= 256 * 128;
  if (idx >= 8 * 65536) return;
  int region = idx >> 16;                        // 0..7
  int rem = idx & 65535;
  int l = region >> 2, m = region & 3;           // m=0 self, else rel m-1
  int nn = rem >> 8, kk = rem & 255;
  const float* wsrc = (m == 0) ? (self_w + (size_t)l * 65536)
                               : (rel_w + ((size_t)l * 3 + (m - 1)) * 65536);
  unsigned short* wdst = (l ? wt_l1 : wt_l0) + (size_t)m * 65536;
  wdst[rem] = f2bf(wsrc[kk * 256 + nn]);
}

// ---------------- CSR build (by dst) ----------------
__global__ __launch_bounds__(256) void histo_kernel(
    const int* __restrict__ dst, int* __restrict__ deg, int E)
{
  int e = blockIdx.x * 256 + threadIdx.x;
  if (e < E) atomicAdd(&deg[dst[e]], 1);
}

__global__ __launch_bounds__(256) void scan_partial(
    const int* __restrict__ deg, int* __restrict__ incl, int* __restrict__ bsum, int N)
{
  __shared__ int s[256];
  int t = threadIdx.x;
  int n = blockIdx.x * 256 + t;
  int v = (n < N) ? deg[n] : 0;
  s[t] = v;
  __syncthreads();
#pragma unroll
  for (int o = 1; o < 256; o <<= 1) {
    int u = (t >= o) ? s[t - o] : 0;
    __syncthreads();
    s[t] += u;
    __syncthreads();
  }
  if (n < N) incl[n] = s[t];
  if (t == 255) bsum[blockIdx.x] = s[255];
}

__global__ __launch_bounds__(256) void scan_sums(int* __restrict__ bsum, int nb)
{
  __shared__ int s[256];
  int t = threadIdx.x;
  int v = (t < nb) ? bsum[t] : 0;
  s[t] = v;
  __syncthreads();
#pragma unroll
  for (int o = 1; o < 256; o <<= 1) {
    int u = (t >= o) ? s[t - o] : 0;
    __syncthreads();
    s[t] += u;
    __syncthreads();
  }
  if (t < nb) bsum[t] = s[t] - v;  // exclusive
}

__global__ __launch_bounds__(256) void scan_add(
    const int* __restrict__ incl, const int* __restrict__ deg,
    const int* __restrict__ bsum, int* __restrict__ off, int N, int E)
{
  int n = blockIdx.x * 256 + threadIdx.x;
  if (n < N) off[n] = incl[n] - deg[n] + bsum[n >> 8];
  if (n == 0) off[N] = E;
}

__global__ __launch_bounds__(256) void fill_kernel(
    const int* __restrict__ src, const int* __restrict__ dst,
    const int* __restrict__ et, const int* __restrict__ off,
    int* __restrict__ cursor, int* __restrict__ psrc, int* __restrict__ prel, int E)
{
  int e = blockIdx.x * 256 + threadIdx.x;
  if (e >= E) return;
  int d = dst[e];
  int pos = atomicAdd(&cursor[d], 1);
  int idx = off[d] + pos;
  psrc[idx] = src[e];
  prel[idx] = et[e];
}

// ---------------- aggregation ----------------
// xout[n] = bf16(relu(self(yb[n, 0:256]) + sum_in-edges yb[src, 256 + r*256 + :]))
__global__ __launch_bounds__(256) void aggregate_kernel(
    const int* __restrict__ off, const int* __restrict__ psrc,
    const int* __restrict__ prel, const unsigned short* __restrict__ yb,
    unsigned short* __restrict__ xout, int N)
{
  int n = blockIdx.x * 4 + (threadIdx.x >> 6);
  if (n >= N) return;
  int lane = threadIdx.x & 63;
  uint2 s = *(const uint2*)(yb + (size_t)n * 1024 + lane * 4);
  float4 acc;
  acc.x = bf2f(s.x & 0xFFFF); acc.y = bf2f(s.x >> 16);
  acc.z = bf2f(s.y & 0xFFFF); acc.w = bf2f(s.y >> 16);
  int i0 = off[n], i1 = off[n + 1];
  for (int i = i0; i < i1; ++i) {
    int sn = psrc[i], rr = prel[i];
    uint2 u = *(const uint2*)(yb + (size_t)sn * 1024 + 256 + rr * 256 + lane * 4);
    acc.x += bf2f(u.x & 0xFFFF); acc.y += bf2f(u.x >> 16);
    acc.z += bf2f(u.y & 0xFFFF); acc.w += bf2f(u.y >> 16);
  }
  ushort4 o;
  o.x = f2bf(fmaxf(acc.x, 0.f)); o.y = f2bf(fmaxf(acc.y, 0.f));
  o.z = f2bf(fmaxf(acc.z, 0.f)); o.w = f2bf(fmaxf(acc.w, 0.f));
  *(ushort4*)(xout + (size_t)n * 256 + lane * 4) = o;
}

// ---------------- mean-pool (input already relu'd bf16) ----------------
__global__ __launch_bounds__(256) void pool_kernel(
    const unsigned short* __restrict__ xb, const int* __restrict__ bv,
    float* __restrict__ hg, float* __restrict__ cnt, int N)
{
  __shared__ int sbv[128];
  int n0 = blockIdx.x * 128;
  int t = threadIdx.x;
  int nmax = min(128, N - n0);
  if (t < nmax) sbv[t] = bv[n0 + t];
  __syncthreads();
  float run = 0.f;
  int cur = sbv[0];
  for (int i = 0; i < nmax; ++i) {
    int b = sbv[i];
    if (b != cur) { atomicAdd(&hg[cur * GDIM + t], run); run = 0.f; cur = b; }
    run += bf2f(xb[(size_t)(n0 + i) * GDIM + t]);
  }
  atomicAdd(&hg[cur * GDIM + t], run);
  if (t == 0) {
    float c = 0.f; int cb = sbv[0];
    for (int i = 0; i < nmax; ++i) {
      int b = sbv[i];
      if (b != cb) { atomicAdd(&cnt[cb], c); c = 0.f; cb = b; }
      c += 1.f;
    }
    atomicAdd(&cnt[cb], c);
  }
}

// ---------------- small dense layers: split-K partials + epilogues ----------------
// optional cntp: scale partial by 1/max(cnt[b],1) (fuses mean-normalize into graph proj)
__global__ __launch_bounds__(256) void smallgemm_partial(
    const float* __restrict__ X, const float* __restrict__ W,
    float* __restrict__ partial, int K, int Ncols, int KC,
    const float* __restrict__ cntp)
{
  int j  = blockIdx.x * 256 + threadIdx.x;
  int b  = blockIdx.y;
  int ks = blockIdx.z;
  if (j >= Ncols) return;
  int k0 = ks * KC, k1 = min(K, k0 + KC);
  const float* xr = X + (size_t)b * K;
  float s0 = 0.f, s1 = 0.f, s2 = 0.f, s3 = 0.f;
  int k = k0;
  for (; k + 4 <= k1; k += 4) {
    s0 = fmaf(xr[k + 0], W[(size_t)(k + 0) * Ncols + j], s0);
    s1 = fmaf(xr[k + 1], W[(size_t)(k + 1) * Ncols + j], s1);
    s2 = fmaf(xr[k + 2], W[(size_t)(k + 2) * Ncols + j], s2);
    s3 = fmaf(xr[k + 3], W[(size_t)(k + 3) * Ncols + j], s3);
  }
  for (; k < k1; ++k) s0 = fmaf(xr[k], W[(size_t)k * Ncols + j], s0);
  float s = (s0 + s1) + (s2 + s3);
  if (cntp) s *= 1.f / fmaxf(cntp[b], 1.f);
  partial[((size_t)ks * gridDim.y + b) * Ncols + j] = s;
}

__global__ __launch_bounds__(256) void ep_sum(
    const float* __restrict__ partial, const float* __restrict__ bias,
    float* __restrict__ out, float* __restrict__ out2,
    int Ncols, int KS, int relu, int ld2, int off2)
{
  int j = blockIdx.x * 256 + threadIdx.x;
  int b = blockIdx.y;
  if (j >= Ncols) return;
  float s = bias ? bias[j] : 0.f;
  for (int ks = 0; ks < KS; ++ks)
    s += partial[((size_t)ks * gridDim.y + b) * Ncols + j];
  if (relu) s = fmaxf(s, 0.f);
  out[(size_t)b * Ncols + j] = s;
  if (out2) out2[(size_t)b * ld2 + off2 + j] = s;
}

__global__ __launch_bounds__(256) void ep_gate(
    const float* __restrict__ partial, const float* __restrict__ gb,
    const float* __restrict__ h, const float* __restrict__ hgp,
    float* __restrict__ f, int KS)
{
  int j = blockIdx.x * 256 + threadIdx.x;  // < 512
  int b = blockIdx.y;
  float s = gb[j];
  for (int ks = 0; ks < KS; ++ks)
    s += partial[((size_t)ks * gridDim.y + b) * HDIM + j];
  float g = 1.f / (1.f + expf(-s));
  f[(size_t)b * HDIM + j] = g * h[(size_t)b * HDIM + j] + (1.f - g) * hgp[(size_t)b * HDIM + j];
}

__global__ __launch_bounds__(256) void c2_kernel(
    const float* __restrict__ z, const float* __restrict__ w,
    const float* __restrict__ bias, float* __restrict__ out)
{
  __shared__ float r0[256], r1[256];
  int b = blockIdx.x, t = threadIdx.x;
  float zv = z[(size_t)b * 256 + t];
  r0[t] = zv * w[t * 2 + 0];
  r1[t] = zv * w[t * 2 + 1];
  __syncthreads();
  for (int o = 128; o > 0; o >>= 1) {
    if (t < o) { r0[t] += r0[t + o]; r1[t] += r1[t + o]; }
    __syncthreads();
  }
  if (t == 0) {
    out[b * 2 + 0] = r0[0] + bias[0];
    out[b * 2 + 1] = r1[0] + bias[1];
  }
}

extern "C" void kernel_launch(void* const* d_in, const int* in_sizes, int n_in,
                              void* d_out, int out_size, void* d_ws, size_t ws_size,
                              hipStream_t stream)
{
  const float* cls     = (const float*)d_in[0];
  const float* nf      = (const float*)d_in[1];
  const int*   ei      = (const int*)d_in[2];
  const int*   et      = (const int*)d_in[3];
  const int*   bv      = (const int*)d_in[4];
  const float* node_w  = (const float*)d_in[5];
  const float* node_b  = (const float*)d_in[6];
  const float* rel_w   = (const float*)d_in[7];
  const float* self_w  = (const float*)d_in[8];
  const float* self_b  = (const float*)d_in[9];
  const float* text_w  = (const float*)d_in[10];
  const float* text_b  = (const float*)d_in[11];
  const float* graph_w = (const float*)d_in[12];
  const float* graph_b = (const float*)d_in[13];
  const float* gate_w  = (const float*)d_in[14];
  const float* gate_b  = (const float*)d_in[15];
  const float* c1_w    = (const float*)d_in[16];
  const float* c1_b    = (const float*)d_in[17];
  const float* c2_w    = (const float*)d_in[18];
  const float* c2_b    = (const float*)d_in[19];

  const int Bsz = in_sizes[0] / 768;   // 64
  const int Nn  = in_sizes[1] / NF;    // 50000
  const int E   = in_sizes[3];         // 300000

  const int* src = ei;
  const int* dst = ei + E;

  // ---------------- workspace layout (floats) ----------------
  float* ws = (float*)d_ws;
  size_t off_f = 0;
  unsigned short* yb  = (unsigned short*)(ws + off_f); off_f += (size_t)Nn * 1024 / 2;  // [N][1024] bf16
  unsigned short* xb1 = (unsigned short*)(ws + off_f); off_f += (size_t)Nn * GDIM / 2;  // [N][256] bf16
  unsigned short* xb2 = (unsigned short*)(ws + off_f); off_f += (size_t)Nn * GDIM / 2;  // [N][256] bf16
  float* h   = ws + off_f; off_f += (size_t)Bsz * HDIM;
  float* hg  = ws + off_f; off_f += (size_t)Bsz * GDIM;
  float* cnt = ws + off_f; off_f += (size_t)Bsz;
  float* hgp = ws + off_f; off_f += (size_t)Bsz * HDIM;
  float* f   = ws + off_f; off_f += (size_t)Bsz * HDIM;
  float* z   = ws + off_f; off_f += (size_t)Bsz * (HDIM/2);
  float* hcat= ws + off_f; off_f += (size_t)Bsz * 2 * HDIM;
  float* pp  = ws + off_f; off_f += (size_t)8 * Bsz * HDIM;
  unsigned short* wt_node = (unsigned short*)(ws + off_f); off_f += (GDIM * NF) / 2;
  unsigned short* wt_l0   = (unsigned short*)(ws + off_f); off_f += (4 * GDIM * GDIM) / 2;
  unsigned short* wt_l1   = (unsigned short*)(ws + off_f); off_f += (4 * GDIM * GDIM) / 2;
  // persistent CSR
  int* csr_off = (int*)(ws + off_f);          // N+1
  int* psrc    = csr_off + (Nn + 1);          // E
  int* prel    = psrc + E;                    // E
  // transient CSR-build scratch overlaid on yb (yb first written by layer-0 GEMM)
  int* deg    = (int*)yb;       // N
  int* incl   = deg + Nn;       // N
  int* cursor = incl + Nn;      // N
  int* bsum   = cursor + Nn;    // 256
  // nf bf16 overlaid on xb2 (consumed by node proj before xb2 is first written)
  unsigned short* nfb = xb2;

  dim3 blk(256);
  const int nbN = (Nn + 255) / 256;
  const int nbE = (E + 255) / 256;
  const int nrb = (Nn + 127) / 128;    // 391 row panels
  const int KC  = 128;

  // ---------------- CSR build (once; reused by both layers) ----------------
  hipMemsetAsync(deg, 0, (size_t)(3 * Nn + 256) * sizeof(int), stream);
  histo_kernel<<<nbE, blk, 0, stream>>>(dst, deg, E);
  scan_partial<<<nbN, blk, 0, stream>>>(deg, incl, bsum, Nn);
  scan_sums<<<1, blk, 0, stream>>>(bsum, nbN);
  scan_add<<<nbN, blk, 0, stream>>>(incl, deg, bsum, csr_off, Nn, E);
  fill_kernel<<<nbE, blk, 0, stream>>>(src, dst, et, csr_off, cursor, psrc, prel, E);

  // weight prep (one launch, 9 transposes)
  prep_all<<<(256 * 128 + 8 * 65536 + 255) / 256, blk, 0, stream>>>(
      node_w, self_w, rel_w, wt_node, wt_l0, wt_l1);

  // zero pooled accumulators (hg, cnt contiguous)
  hipMemsetAsync(hg, 0, (size_t)(Bsz * GDIM + Bsz) * sizeof(float), stream);

  // text projection (split-K) -> h and hcat[:, :512]
  smallgemm_partial<<<dim3(2, Bsz, 6), blk, 0, stream>>>(cls, text_w, pp, 768, HDIM, KC, nullptr);
  ep_sum<<<dim3(2, Bsz), blk, 0, stream>>>(pp, text_b, h, hcat, HDIM, 6, 0, 2 * HDIM, 0);

  // node projection: xb1 = bf16(nf @ node_w + node_b)
  convert_bf16<<<(Nn * NF) / 4 / 256, blk, 0, stream>>>(nf, nfb, Nn * NF);
  mfma_gemm<<<dim3(nrb * 2), blk, 0, stream>>>(nfb, wt_node, node_b, xb1, Nn, NF, 256, 256, 2);

  // RGCN layer 0: yb = xb1 @ [self|rel0|rel1|rel2]; aggregate -> xb2 (relu bf16)
  mfma_gemm<<<dim3(nrb * 8), blk, 0, stream>>>(xb1, wt_l0, self_b, yb, Nn, GDIM, 1024, 256, 8);
  aggregate_kernel<<<dim3((Nn + 3) / 4), blk, 0, stream>>>(csr_off, psrc, prel, yb, xb2, Nn);

  // RGCN layer 1: yb = xb2 @ [...]; aggregate -> xb1 (relu bf16)
  mfma_gemm<<<dim3(nrb * 8), blk, 0, stream>>>(xb2, wt_l1, self_b + GDIM, yb, Nn, GDIM, 1024, 256, 8);
  aggregate_kernel<<<dim3((Nn + 3) / 4), blk, 0, stream>>>(csr_off, psrc, prel, yb, xb1, Nn);

  // mean pool (input already relu'd)
  pool_kernel<<<dim3((Nn + 127) / 128), blk, 0, stream>>>(xb1, bv, hg, cnt, Nn);

  // graph projection (mean-normalize fused via cnt) -> hgp and hcat[:, 512:]
  smallgemm_partial<<<dim3(2, Bsz, 2), blk, 0, stream>>>(hg, graph_w, pp, GDIM, HDIM, KC, cnt);
  ep_sum<<<dim3(2, Bsz), blk, 0, stream>>>(pp, graph_b, hgp, hcat, HDIM, 2, 0, 2 * HDIM, HDIM);

  // gated fusion
  smallgemm_partial<<<dim3(2, Bsz, 8), blk, 0, stream>>>(hcat, gate_w, pp, 2 * HDIM, HDIM, KC, nullptr);
  ep_gate<<<dim3(2, Bsz), blk, 0, stream>>>(pp, gate_b, h, hgp, f, 8);

  // classifier
  smallgemm_partial<<<dim3(1, Bsz, 4), blk, 0, stream>>>(f, c1_w, pp, HDIM, HDIM / 2, KC, nullptr);
  ep_sum<<<dim3(1, Bsz), blk, 0, stream>>>(pp, c1_b, z, nullptr, HDIM / 2, 4, 1, 0, 0);
  c2_kernel<<<dim3(Bsz), blk, 0, stream>>>(z, c2_w, c2_b, (float*)d_out);
}

// Round 12
// 504.816 us; speedup vs baseline: 6.9308x; 1.0462x over previous
//
#include <hip/hip_runtime.h>
#include <hip/hip_bf16.h>
#include <cstdint>
#include <cstddef>

// Problem constants (VulnDetector): B=64, N=50000, E=300000, NF=128, G=256, H=512, R=3, L=2
constexpr int GDIM = 256;   // graph hidden
constexpr int HDIM = 512;   // fusion hidden
constexpr int NF   = 128;   // node features

typedef __attribute__((ext_vector_type(8))) short bf16x8;
typedef __attribute__((ext_vector_type(4))) float f32x4;

__device__ __forceinline__ unsigned short f2bf(float x) {
  union { float f; unsigned int u; } v; v.f = x;
  unsigned int r = v.u + 0x7FFF + ((v.u >> 16) & 1);   // RNE
  return (unsigned short)(r >> 16);
}
__device__ __forceinline__ float bf2f(unsigned int h) {
  union { unsigned int u; float f; } v; v.u = h << 16; return v.f;
}

__device__ __forceinline__ void gload16(const void* g, void* l) {
  __builtin_amdgcn_global_load_lds(
      (const __attribute__((address_space(1))) unsigned int*)g,
      (__attribute__((address_space(3))) unsigned int*)l, 16, 0, 0);
}

// ---------------- bf16 MFMA GEMM (double-buffered 2-phase) ----------------
// out[M][ldout]bf16 = act(A[M,K]bf16 @ Wt[256,K]bf16^T + bias), NOUT=256 (ncb=2).
// 1D grid = nrb*2; bijective XCD swizzle (m204) + col-fastest decode (A panel L2-local).
// K-loop: prefetch tile t+1 into the other LDS buffer BEFORE computing tile t;
// single __syncthreads per iter (= vmcnt(0)+barrier) drains the prefetch after
// it has overlapped with 32 MFMAs of compute.
__global__ __launch_bounds__(256) void mfma_gemm(
    const unsigned short* __restrict__ A, const unsigned short* __restrict__ Wt,
    const float* __restrict__ bias, unsigned short* __restrict__ out,
    int M, int K, int ldout, int relu)
{
  __shared__ __align__(16) unsigned short lds[2 * 2 * 128 * 64];  // 2 bufs x (A 16KB | B 16KB)
  char* ldsb = (char*)lds;
  const int nwg  = gridDim.x;
  const int orig = blockIdx.x;
  const int q = nwg >> 3, r = nwg & 7;
  const int xcd = orig & 7, sidx = orig >> 3;
  const int wgid = (xcd < r ? xcd * (q + 1) : r * (q + 1) + (xcd - r) * q) + sidx;
  const int row0 = (wgid >> 1) * 128;
  const int n0   = (wgid & 1) * 128;

  const int t    = threadIdx.x;
  const int lane = t & 63;
  const int w    = t >> 6;
  const int wr   = w >> 1, wc = w & 1;

  f32x4 acc[4][4] = {};

  // staging: issue i, wave w covers LDS bytes [(i*4+w)*1024, +1024), row stride 128 B
  const int srow  = lane >> 3;
  const int sslot = lane & 7;

  auto stage = [&](int buf, int k0) {
#pragma unroll
    for (int i = 0; i < 4; ++i) {
      int row  = (i * 4 + w) * 8 + srow;
      int slot = sslot ^ (row & 7);            // pre-swizzled global source (m173 pattern)
      int grA  = min(row0 + row, M - 1);
      gload16(A  + (size_t)grA        * K + k0 + slot * 8,
              ldsb + buf * 32768 + (i * 4 + w) * 1024);
      gload16(Wt + (size_t)(n0 + row) * K + k0 + slot * 8,
              ldsb + buf * 32768 + 16384 + (i * 4 + w) * 1024);
    }
  };

  stage(0, 0);
  __syncthreads();                 // drain prologue loads (vmcnt(0) + barrier)

  const int nk = K >> 6;
  int cur = 0;
  for (int kt = 0; kt < nk; ++kt) {
    if (kt + 1 < nk) stage(cur ^ 1, (kt + 1) << 6);   // prefetch overlaps compute below
    char* base = ldsb + cur * 32768;
#pragma unroll
    for (int kc = 0; kc < 2; ++kc) {
      bf16x8 af[4], bfr[4];
#pragma unroll
      for (int m = 0; m < 4; ++m) {
        int row  = wr * 64 + m * 16 + (lane & 15);
        int slot = (kc * 4 + (lane >> 4)) ^ (row & 7);   // swizzled read
        af[m] = *(const bf16x8*)(base + row * 128 + slot * 16);
      }
#pragma unroll
      for (int n = 0; n < 4; ++n) {
        int row  = wc * 64 + n * 16 + (lane & 15);
        int slot = (kc * 4 + (lane >> 4)) ^ (row & 7);
        bfr[n] = *(const bf16x8*)(base + 16384 + row * 128 + slot * 16);
      }
#pragma unroll
      for (int m = 0; m < 4; ++m)
#pragma unroll
        for (int n = 0; n < 4; ++n)
          acc[m][n] = __builtin_amdgcn_mfma_f32_16x16x32_bf16(af[m], bfr[n], acc[m][n], 0, 0, 0);
    }
    if (kt + 1 < nk) { __syncthreads(); cur ^= 1; }   // prefetched tile now resident
  }

  // epilogue: C/D layout col=lane&15, row=(lane>>4)*4+reg; bf16 out, bias(+relu)
#pragma unroll
  for (int m = 0; m < 4; ++m) {
    int rbase = row0 + wr * 64 + m * 16 + (lane >> 4) * 4;
#pragma unroll
    for (int n = 0; n < 4; ++n) {
      int c = n0 + wc * 64 + n * 16 + (lane & 15);
      float badd = bias[c];
#pragma unroll
      for (int i = 0; i < 4; ++i) {
        int rr = rbase + i;
        if (rr < M) {
          float v = acc[m][n][i] + badd;
          if (relu) v = fmaxf(v, 0.f);
          out[(size_t)rr * ldout + c] = f2bf(v);
        }
      }
    }
  }
}

// ---------------- converts / weight prep ----------------
__global__ __launch_bounds__(256) void convert_bf16(
    const float* __restrict__ x, unsigned short* __restrict__ xb, int n)
{
  int i = (blockIdx.x * 256 + threadIdx.x) * 4;
  if (i >= n) return;
  float4 v = *(const float4*)(x + i);
  ushort4 o; o.x = f2bf(v.x); o.y = f2bf(v.y); o.z = f2bf(v.z); o.w = f2bf(v.w);
  *(ushort4*)(xb + i) = o;
}

// weight prep: wt_node[n][k]=node_w[k][n] (256x128); per layer K-stacked
// wtcat_l[n][k], k<256 -> self_w[l][k][n]; k>=256 -> rel_w[l][(k>>8)-1][k&255][n]
__global__ __launch_bounds__(256) void prep_all(
    const float* __restrict__ node_w, const float* __restrict__ self_w,
    const float* __restrict__ rel_w, unsigned short* __restrict__ wt_node,
    unsigned short* __restrict__ wt_l0, unsigned short* __restrict__ wt_l1)
{
  int idx = blockIdx.x * 256 + threadIdx.x;
  if (idx < 256 * 128) {
    int nn = idx >> 7, kk = idx & 127;
    wt_node[idx] = f2bf(node_w[kk * 256 + nn]);
    return;
  }
  idx -= 256 * 128;
  if (idx >= 2 * 256 * 1024) return;
  int l = idx >> 18;                       // 0..1
  int rem = idx & 262143;                  // n*1024 + k
  int nn = rem >> 10, k = rem & 1023;
  float v;
  if (k < 256) v = self_w[(size_t)l * 65536 + k * 256 + nn];
  else {
    int r = (k >> 8) - 1, kk = k & 255;
    v = rel_w[((size_t)l * 3 + r) * 65536 + kk * 256 + nn];
  }
  (l ? wt_l1 : wt_l0)[rem] = f2bf(v);
}

// ---------------- CSR build (by dst) ----------------
__global__ __launch_bounds__(256) void histo_kernel(
    const int* __restrict__ dst, int* __restrict__ deg, int E)
{
  int e = blockIdx.x * 256 + threadIdx.x;
  if (e < E) atomicAdd(&deg[dst[e]], 1);
}

__global__ __launch_bounds__(256) void scan_partial(
    const int* __restrict__ deg, int* __restrict__ incl, int* __restrict__ bsum, int N)
{
  __shared__ int s[256];
  int t = threadIdx.x;
  int n = blockIdx.x * 256 + t;
  int v = (n < N) ? deg[n] : 0;
  s[t] = v;
  __syncthreads();
#pragma unroll
  for (int o = 1; o < 256; o <<= 1) {
    int u = (t >= o) ? s[t - o] : 0;
    __syncthreads();
    s[t] += u;
    __syncthreads();
  }
  if (n < N) incl[n] = s[t];
  if (t == 255) bsum[blockIdx.x] = s[255];
}

__global__ __launch_bounds__(256) void scan_sums(int* __restrict__ bsum, int nb)
{
  __shared__ int s[256];
  int t = threadIdx.x;
  int v = (t < nb) ? bsum[t] : 0;
  s[t] = v;
  __syncthreads();
#pragma unroll
  for (int o = 1; o < 256; o <<= 1) {
    int u = (t >= o) ? s[t - o] : 0;
    __syncthreads();
    s[t] += u;
    __syncthreads();
  }
  if (t < nb) bsum[t] = s[t] - v;  // exclusive
}

__global__ __launch_bounds__(256) void scan_add(
    const int* __restrict__ incl, const int* __restrict__ deg,
    const int* __restrict__ bsum, int* __restrict__ off, int N, int E)
{
  int n = blockIdx.x * 256 + threadIdx.x;
  if (n < N) off[n] = incl[n] - deg[n] + bsum[n >> 8];
  if (n == 0) off[N] = E;
}

__global__ __launch_bounds__(256) void fill_kernel(
    const int* __restrict__ src, const int* __restrict__ dst,
    const int* __restrict__ et, const int* __restrict__ off,
    int* __restrict__ cursor, int* __restrict__ psrc, int* __restrict__ prel, int E)
{
  int e = blockIdx.x * 256 + threadIdx.x;
  if (e >= E) return;
  int d = dst[e];
  int pos = atomicAdd(&cursor[d], 1);
  int idx = off[d] + pos;
  psrc[idx] = src[e];
  prel[idx] = et[e];
}

// ---------------- pre-transform aggregation ----------------
// xcat[n][256 + r*256 + c] = sum over incoming edges (rel r) of xcat[src][c]
// (reads cols 0:256 = x; writes cols 256:1024; disjoint -> safe in-place)
// Relation is wave-uniform per edge -> uniform branch, named accumulators.
__global__ __launch_bounds__(256) void aggregate_kernel(
    const int* __restrict__ off, const int* __restrict__ psrc,
    const int* __restrict__ prel, unsigned short* __restrict__ xcat, int N)
{
  int n = blockIdx.x * 4 + (threadIdx.x >> 6);
  if (n >= N) return;
  int lane = threadIdx.x & 63;
  float4 a0 = {0.f, 0.f, 0.f, 0.f}, a1 = a0, a2 = a0;
  int i0 = off[n], i1 = off[n + 1];
  for (int i = i0; i < i1; ++i) {
    int sn = psrc[i], rr = prel[i];
    uint2 u = *(const uint2*)(xcat + (size_t)sn * 1024 + lane * 4);
    float4 v;
    v.x = bf2f(u.x & 0xFFFF); v.y = bf2f(u.x >> 16);
    v.z = bf2f(u.y & 0xFFFF); v.w = bf2f(u.y >> 16);
    if (rr == 0)      { a0.x += v.x; a0.y += v.y; a0.z += v.z; a0.w += v.w; }
    else if (rr == 1) { a1.x += v.x; a1.y += v.y; a1.z += v.z; a1.w += v.w; }
    else              { a2.x += v.x; a2.y += v.y; a2.z += v.z; a2.w += v.w; }
  }
  unsigned short* o = xcat + (size_t)n * 1024 + 256 + lane * 4;
  ushort4 s0, s1, s2;
  s0.x = f2bf(a0.x); s0.y = f2bf(a0.y); s0.z = f2bf(a0.z); s0.w = f2bf(a0.w);
  s1.x = f2bf(a1.x); s1.y = f2bf(a1.y); s1.z = f2bf(a1.z); s1.w = f2bf(a1.w);
  s2.x = f2bf(a2.x); s2.y = f2bf(a2.y); s2.z = f2bf(a2.z); s2.w = f2bf(a2.w);
  *(ushort4*)(o)       = s0;
  *(ushort4*)(o + 256) = s1;
  *(ushort4*)(o + 512) = s2;
}

// ---------------- mean-pool (input already relu'd bf16, [N][256]) ----------------
__global__ __launch_bounds__(256) void pool_kernel(
    const unsigned short* __restrict__ xb, const int* __restrict__ bv,
    float* __restrict__ hg, float* __restrict__ cnt, int N)
{
  __shared__ int sbv[128];
  int n0 = blockIdx.x * 128;
  int t = threadIdx.x;
  int nmax = min(128, N - n0);
  if (t < nmax) sbv[t] = bv[n0 + t];
  __syncthreads();
  float run = 0.f;
  int cur = sbv[0];
  for (int i = 0; i < nmax; ++i) {
    int b = sbv[i];
    if (b != cur) { atomicAdd(&hg[cur * GDIM + t], run); run = 0.f; cur = b; }
    run += bf2f(xb[(size_t)(n0 + i) * GDIM + t]);
  }
  atomicAdd(&hg[cur * GDIM + t], run);
  if (t == 0) {
    float c = 0.f; int cb = sbv[0];
    for (int i = 0; i < nmax; ++i) {
      int b = sbv[i];
      if (b != cb) { atomicAdd(&cnt[cb], c); c = 0.f; cb = b; }
      c += 1.f;
    }
    atomicAdd(&cnt[cb], c);
  }
}

// ---------------- small dense layers: split-K partials + epilogues ----------------
__global__ __launch_bounds__(256) void smallgemm_partial(
    const float* __restrict__ X, const float* __restrict__ W,
    float* __restrict__ partial, int K, int Ncols, int KC,
    const float* __restrict__ cntp)
{
  int j  = blockIdx.x * 256 + threadIdx.x;
  int b  = blockIdx.y;
  int ks = blockIdx.z;
  if (j >= Ncols) return;
  int k0 = ks * KC, k1 = min(K, k0 + KC);
  const float* xr = X + (size_t)b * K;
  float s0 = 0.f, s1 = 0.f, s2 = 0.f, s3 = 0.f;
  int k = k0;
  for (; k + 4 <= k1; k += 4) {
    s0 = fmaf(xr[k + 0], W[(size_t)(k + 0) * Ncols + j], s0);
    s1 = fmaf(xr[k + 1], W[(size_t)(k + 1) * Ncols + j], s1);
    s2 = fmaf(xr[k + 2], W[(size_t)(k + 2) * Ncols + j], s2);
    s3 = fmaf(xr[k + 3], W[(size_t)(k + 3) * Ncols + j], s3);
  }
  for (; k < k1; ++k) s0 = fmaf(xr[k], W[(size_t)k * Ncols + j], s0);
  float s = (s0 + s1) + (s2 + s3);
  if (cntp) s *= 1.f / fmaxf(cntp[b], 1.f);
  partial[((size_t)ks * gridDim.y + b) * Ncols + j] = s;
}

__global__ __launch_bounds__(256) void ep_sum(
    const float* __restrict__ partial, const float* __restrict__ bias,
    float* __restrict__ out, float* __restrict__ out2,
    int Ncols, int KS, int relu, int ld2, int off2)
{
  int j = blockIdx.x * 256 + threadIdx.x;
  int b = blockIdx.y;
  if (j >= Ncols) return;
  float s = bias ? bias[j] : 0.f;
  for (int ks = 0; ks < KS; ++ks)
    s += partial[((size_t)ks * gridDim.y + b) * Ncols + j];
  if (relu) s = fmaxf(s, 0.f);
  out[(size_t)b * Ncols + j] = s;
  if (out2) out2[(size_t)b * ld2 + off2 + j] = s;
}

__global__ __launch_bounds__(256) void ep_gate(
    const float* __restrict__ partial, const float* __restrict__ gb,
    const float* __restrict__ h, const float* __restrict__ hgp,
    float* __restrict__ f, int KS)
{
  int j = blockIdx.x * 256 + threadIdx.x;  // < 512
  int b = blockIdx.y;
  float s = gb[j];
  for (int ks = 0; ks < KS; ++ks)
    s += partial[((size_t)ks * gridDim.y + b) * HDIM + j];
  float g = 1.f / (1.f + expf(-s));
  f[(size_t)b * HDIM + j] = g * h[(size_t)b * HDIM + j] + (1.f - g) * hgp[(size_t)b * HDIM + j];
}

__global__ __launch_bounds__(256) void c2_kernel(
    const float* __restrict__ z, const float* __restrict__ w,
    const float* __restrict__ bias, float* __restrict__ out)
{
  __shared__ float r0[256], r1[256];
  int b = blockIdx.x, t = threadIdx.x;
  float zv = z[(size_t)b * 256 + t];
  r0[t] = zv * w[t * 2 + 0];
  r1[t] = zv * w[t * 2 + 1];
  __syncthreads();
  for (int o = 128; o > 0; o >>= 1) {
    if (t < o) { r0[t] += r0[t + o]; r1[t] += r1[t + o]; }
    __syncthreads();
  }
  if (t == 0) {
    out[b * 2 + 0] = r0[0] + bias[0];
    out[b * 2 + 1] = r1[0] + bias[1];
  }
}

extern "C" void kernel_launch(void* const* d_in, const int* in_sizes, int n_in,
                              void* d_out, int out_size, void* d_ws, size_t ws_size,
                              hipStream_t stream)
{
  const float* cls     = (const float*)d_in[0];
  const float* nf      = (const float*)d_in[1];
  const int*   ei      = (const int*)d_in[2];
  const int*   et      = (const int*)d_in[3];
  const int*   bv      = (const int*)d_in[4];
  const float* node_w  = (const float*)d_in[5];
  const float* node_b  = (const float*)d_in[6];
  const float* rel_w   = (const float*)d_in[7];
  const float* self_w  = (const float*)d_in[8];
  const float* self_b  = (const float*)d_in[9];
  const float* text_w  = (const float*)d_in[10];
  const float* text_b  = (const float*)d_in[11];
  const float* graph_w = (const float*)d_in[12];
  const float* graph_b = (const float*)d_in[13];
  const float* gate_w  = (const float*)d_in[14];
  const float* gate_b  = (const float*)d_in[15];
  const float* c1_w    = (const float*)d_in[16];
  const float* c1_b    = (const float*)d_in[17];
  const float* c2_w    = (const float*)d_in[18];
  const float* c2_b    = (const float*)d_in[19];

  const int Bsz = in_sizes[0] / 768;   // 64
  const int Nn  = in_sizes[1] / NF;    // 50000
  const int E   = in_sizes[3];         // 300000

  const int* src = ei;
  const int* dst = ei + E;

  // ---------------- workspace layout (floats) ----------------
  float* ws = (float*)d_ws;
  size_t off_f = 0;
  unsigned short* xcat0 = (unsigned short*)(ws + off_f); off_f += (size_t)Nn * 1024 / 2; // [N][1024]
  unsigned short* xcat1 = (unsigned short*)(ws + off_f); off_f += (size_t)Nn * 1024 / 2; // [N][1024]
  unsigned short* xbf   = (unsigned short*)(ws + off_f); off_f += (size_t)Nn * GDIM / 2; // [N][256]
  float* h   = ws + off_f; off_f += (size_t)Bsz * HDIM;
  float* hg  = ws + off_f; off_f += (size_t)Bsz * GDIM;
  float* cnt = ws + off_f; off_f += (size_t)Bsz;
  float* hgp = ws + off_f; off_f += (size_t)Bsz * HDIM;
  float* f   = ws + off_f; off_f += (size_t)Bsz * HDIM;
  float* z   = ws + off_f; off_f += (size_t)Bsz * (HDIM/2);
  float* hcat= ws + off_f; off_f += (size_t)Bsz * 2 * HDIM;
  float* pp  = ws + off_f; off_f += (size_t)8 * Bsz * HDIM;
  unsigned short* wt_node = (unsigned short*)(ws + off_f); off_f += (GDIM * NF) / 2;
  unsigned short* wt_l0   = (unsigned short*)(ws + off_f); off_f += (GDIM * 1024) / 2;
  unsigned short* wt_l1   = (unsigned short*)(ws + off_f); off_f += (GDIM * 1024) / 2;
  // persistent CSR
  int* csr_off = (int*)(ws + off_f);          // N+1
  int* psrc    = csr_off + (Nn + 1);          // E
  int* prel    = psrc + E;                    // E
  // transient CSR-build scratch overlaid on xcat1 (first written by layer-0 GEMM, later)
  int* deg    = (int*)xcat1;    // N
  int* incl   = deg + Nn;       // N
  int* cursor = incl + Nn;      // N
  int* bsum   = cursor + Nn;    // 256
  // nf bf16 overlaid on xcat1 too (dead after node GEMM; stream-ordered after fill)
  unsigned short* nfb = (unsigned short*)(cursor + Nn + 256);

  dim3 blk(256);
  const int nbN = (Nn + 255) / 256;
  const int nbE = (E + 255) / 256;
  const int nrb = (Nn + 127) / 128;    // 391 row panels
  const int KC  = 128;

  // ---------------- CSR build (once; reused by both layers) ----------------
  hipMemsetAsync(deg, 0, (size_t)(3 * Nn + 256) * sizeof(int), stream);
  histo_kernel<<<nbE, blk, 0, stream>>>(dst, deg, E);
  scan_partial<<<nbN, blk, 0, stream>>>(deg, incl, bsum, Nn);
  scan_sums<<<1, blk, 0, stream>>>(bsum, nbN);
  scan_add<<<nbN, blk, 0, stream>>>(incl, deg, bsum, csr_off, Nn, E);
  fill_kernel<<<nbE, blk, 0, stream>>>(src, dst, et, csr_off, cursor, psrc, prel, E);

  // weight prep (one launch: node + 2x K-stacked layer weights)
  prep_all<<<(256 * 128 + 2 * 256 * 1024 + 255) / 256, blk, 0, stream>>>(
      node_w, self_w, rel_w, wt_node, wt_l0, wt_l1);

  // zero pooled accumulators (hg, cnt contiguous)
  hipMemsetAsync(hg, 0, (size_t)(Bsz * GDIM + Bsz) * sizeof(float), stream);

  // text projection (split-K) -> h and hcat[:, :512]
  smallgemm_partial<<<dim3(2, Bsz, 6), blk, 0, stream>>>(cls, text_w, pp, 768, HDIM, KC, nullptr);
  ep_sum<<<dim3(2, Bsz), blk, 0, stream>>>(pp, text_b, h, hcat, HDIM, 6, 0, 2 * HDIM, 0);

  // node projection: xcat0[:, 0:256] = bf16(nf @ node_w + node_b)
  convert_bf16<<<(Nn * NF) / 4 / 256, blk, 0, stream>>>(nf, nfb, Nn * NF);
  mfma_gemm<<<dim3(nrb * 2), blk, 0, stream>>>(nfb, wt_node, node_b, xcat0, Nn, NF, 1024, 0);

  // RGCN layer 0: aggregate x per relation, then one K=1024 GEMM -> xcat1[:, 0:256] (relu)
  aggregate_kernel<<<dim3((Nn + 3) / 4), blk, 0, stream>>>(csr_off, psrc, prel, xcat0, Nn);
  mfma_gemm<<<dim3(nrb * 2), blk, 0, stream>>>(xcat0, wt_l0, self_b, xcat1, Nn, 1024, 1024, 1);

  // RGCN layer 1: aggregate, then GEMM -> xbf[:, 0:256] (relu)
  aggregate_kernel<<<dim3((Nn + 3) / 4), blk, 0, stream>>>(csr_off, psrc, prel, xcat1, Nn);
  mfma_gemm<<<dim3(nrb * 2), blk, 0, stream>>>(xcat1, wt_l1, self_b + GDIM, xbf, Nn, 1024, 256, 1);

  // mean pool (input already relu'd)
  pool_kernel<<<dim3((Nn + 127) / 128), blk, 0, stream>>>(xbf, bv, hg, cnt, Nn);

  // graph projection (mean-normalize fused via cnt) -> hgp and hcat[:, 512:]
  smallgemm_partial<<<dim3(2, Bsz, 2), blk, 0, stream>>>(hg, graph_w, pp, GDIM, HDIM, KC, cnt);
  ep_sum<<<dim3(2, Bsz), blk, 0, stream>>>(pp, graph_b, hgp, hcat, HDIM, 2, 0, 2 * HDIM, HDIM);

  // gated fusion
  smallgemm_partial<<<dim3(2, Bsz, 8), blk, 0, stream>>>(hcat, gate_w, pp, 2 * HDIM, HDIM, KC, nullptr);
  ep_gate<<<dim3(2, Bsz), blk, 0, stream>>>(pp, gate_b, h, hgp, f, 8);

  // classifier
  smallgemm_partial<<<dim3(1, Bsz, 4), blk, 0, stream>>>(f, c1_w, pp, HDIM, HDIM / 2, KC, nullptr);
  ep_sum<<<dim3(1, Bsz), blk, 0, stream>>>(pp, c1_b, z, nullptr, HDIM / 2, 4, 1, 0, 0);
  c2_kernel<<<dim3(Bsz), blk, 0, stream>>>(z, c2_w, c2_b, (float*)d_out);
}